// Round 1
// baseline (3769.793 us; speedup 1.0000x reference)
//
#include <hip/hip_runtime.h>

#define NPTS    2000000
#define NQUADS  500000     // NPTS / 4
#define PIL     100000
#define BN_EPS_F 1e-3f

// d_ws float layout
#define ACC_OFF  0         // 65 floats: m[10], S[55]
#define WP_OFF   128       // 320 floats: W' (folded BN scale)
#define BP_OFF   512       // 32 floats: b'
#define XMAX_OFF 1024      // PIL*32 floats: segment max (uint-ordered fp32)

__device__ __forceinline__ constexpr int tri_idx(int j, int k) {
    // upper-triangular (j<=k) index into 55-entry array
    return j * 10 - j * (j - 1) / 2 + (k - j);
}

// ---------------- Pass 1: input moments (m[10], S[55]) ----------------
__global__ __launch_bounds__(256) void k1_moments(const float* __restrict__ in,
                                                  float* __restrict__ accum)
{
    float m[10], S[55];
#pragma unroll
    for (int i = 0; i < 10; ++i) m[i] = 0.f;
#pragma unroll
    for (int i = 0; i < 55; ++i) S[i] = 0.f;

    const int T = gridDim.x * blockDim.x;
    for (int q = blockIdx.x * blockDim.x + threadIdx.x; q < NQUADS; q += T) {
        const float4* p4 = reinterpret_cast<const float4*>(in + (size_t)q * 40);
        float xf[40];
#pragma unroll
        for (int i = 0; i < 10; ++i) {
            float4 r = p4[i];
            xf[4*i+0] = r.x; xf[4*i+1] = r.y; xf[4*i+2] = r.z; xf[4*i+3] = r.w;
        }
#pragma unroll
        for (int p = 0; p < 4; ++p) {
#pragma unroll
            for (int j = 0; j < 10; ++j) {
                float xj = xf[p*10 + j];
                m[j] += xj;
#pragma unroll
                for (int k = j; k < 10; ++k)
                    S[tri_idx(j, k)] += xj * xf[p*10 + k];
            }
        }
    }

    // wave-level butterfly reduce, one atomicAdd per wave per value
#pragma unroll
    for (int i = 0; i < 10; ++i) {
        float v = m[i];
#pragma unroll
        for (int s = 1; s < 64; s <<= 1) v += __shfl_xor(v, s, 64);
        if ((threadIdx.x & 63) == 0) atomicAdd(accum + i, v);
    }
#pragma unroll
    for (int i = 0; i < 55; ++i) {
        float v = S[i];
#pragma unroll
        for (int s = 1; s < 64; s <<= 1) v += __shfl_xor(v, s, 64);
        if ((threadIdx.x & 63) == 0) atomicAdd(accum + 10 + i, v);
    }
}

// ---------------- Pass 2: finalize BN -> folded W', b' ----------------
__global__ void k2_finalize(const float* __restrict__ accum, const float* __restrict__ W,
                            const float* __restrict__ b, const float* __restrict__ gamma,
                            const float* __restrict__ beta, float* __restrict__ Wp,
                            float* __restrict__ bp)
{
    int c = threadIdx.x;
    if (c >= 32) return;
    const float invN = 1.0f / (float)NPTS;
    float m[10], w[10];
#pragma unroll
    for (int k = 0; k < 10; ++k) m[k] = accum[k] * invN;
#pragma unroll
    for (int k = 0; k < 10; ++k) w[k] = W[c*10 + k];
    float mean = b[c];
#pragma unroll
    for (int k = 0; k < 10; ++k) mean += w[k] * m[k];
    float var = 0.f;
#pragma unroll
    for (int j = 0; j < 10; ++j) {
#pragma unroll
        for (int k = j; k < 10; ++k) {
            float Cjk = accum[10 + tri_idx(j, k)] * invN - m[j] * m[k];
            var += w[j] * w[k] * Cjk * ((j == k) ? 1.f : 2.f);
        }
    }
    float scale = gamma[c] * rsqrtf(var + BN_EPS_F);
#pragma unroll
    for (int k = 0; k < 10; ++k) Wp[c*10 + k] = w[k] * scale;
    bp[c] = (b[c] - mean) * scale + beta[c];
}

// ---------------- Pass 3: recompute x, scatter-max into pillars ----------------
__global__ __launch_bounds__(256) void k3_scatter(const float* __restrict__ in,
                                                  const int* __restrict__ unq,
                                                  const float* __restrict__ Wp,
                                                  const float* __restrict__ bp,
                                                  unsigned int* __restrict__ xmax)
{
    int t = blockIdx.x * blockDim.x + threadIdx.x;
    if (t >= NQUADS) return;
    const float4* p4 = reinterpret_cast<const float4*>(in + (size_t)t * 40);
    float xf[40];
#pragma unroll
    for (int i = 0; i < 10; ++i) {
        float4 r = p4[i];
        xf[4*i+0] = r.x; xf[4*i+1] = r.y; xf[4*i+2] = r.z; xf[4*i+3] = r.w;
    }
    int4 pi = *reinterpret_cast<const int4*>(unq + (size_t)t * 4);
    unsigned base[4] = { (unsigned)pi.x * 32u, (unsigned)pi.y * 32u,
                         (unsigned)pi.z * 32u, (unsigned)pi.w * 32u };
#pragma unroll
    for (int c = 0; c < 32; ++c) {
        float bb = bp[c];
        float a0 = bb, a1 = bb, a2 = bb, a3 = bb;
#pragma unroll
        for (int k = 0; k < 10; ++k) {
            float wv = Wp[c*10 + k];
            a0 += xf[k]      * wv;
            a1 += xf[10 + k] * wv;
            a2 += xf[20 + k] * wv;
            a3 += xf[30 + k] * wv;
        }
        atomicMax(xmax + base[0] + c, __float_as_uint(fmaxf(a0, 0.f)));
        atomicMax(xmax + base[1] + c, __float_as_uint(fmaxf(a1, 0.f)));
        atomicMax(xmax + base[2] + c, __float_as_uint(fmaxf(a2, 0.f)));
        atomicMax(xmax + base[3] + c, __float_as_uint(fmaxf(a3, 0.f)));
    }
}

// ---------------- Pass 4: recompute x, gather pillar max, write output ----------------
__global__ __launch_bounds__(256) void k4_out(const float* __restrict__ in,
                                              const int* __restrict__ unq,
                                              const float* __restrict__ Wp,
                                              const float* __restrict__ bp,
                                              const float* __restrict__ xmax,
                                              float* __restrict__ out)
{
    int t = blockIdx.x * blockDim.x + threadIdx.x;
    if (t >= NQUADS) return;
    const float4* p4 = reinterpret_cast<const float4*>(in + (size_t)t * 40);
    float xf[40];
#pragma unroll
    for (int i = 0; i < 10; ++i) {
        float4 r = p4[i];
        xf[4*i+0] = r.x; xf[4*i+1] = r.y; xf[4*i+2] = r.z; xf[4*i+3] = r.w;
    }
    int4 pi = *reinterpret_cast<const int4*>(unq + (size_t)t * 4);
    int pb[4] = { pi.x, pi.y, pi.z, pi.w };
    float* o = out + (size_t)t * 128;
#pragma unroll
    for (int cq = 0; cq < 8; ++cq) {
        float acc[4][4];  // [point][sub-channel]
#pragma unroll
        for (int j = 0; j < 4; ++j) {
            float bb = bp[cq*4 + j];
#pragma unroll
            for (int p = 0; p < 4; ++p) acc[p][j] = bb;
        }
#pragma unroll
        for (int k = 0; k < 10; ++k) {
#pragma unroll
            for (int j = 0; j < 4; ++j) {
                float wv = Wp[(cq*4 + j)*10 + k];
#pragma unroll
                for (int p = 0; p < 4; ++p) acc[p][j] += xf[p*10 + k] * wv;
            }
        }
#pragma unroll
        for (int p = 0; p < 4; ++p) {
            float4 xm = *reinterpret_cast<const float4*>(xmax + (size_t)pb[p]*32 + cq*4);
            float4 ov;
            ov.x = (fmaxf(acc[p][0], 0.f) + xm.x) * 0.5f;
            ov.y = (fmaxf(acc[p][1], 0.f) + xm.y) * 0.5f;
            ov.z = (fmaxf(acc[p][2], 0.f) + xm.z) * 0.5f;
            ov.w = (fmaxf(acc[p][3], 0.f) + xm.w) * 0.5f;
            *reinterpret_cast<float4*>(o + p*32 + cq*4) = ov;
        }
    }
}

extern "C" void kernel_launch(void* const* d_in, const int* in_sizes, int n_in,
                              void* d_out, int out_size, void* d_ws, size_t ws_size,
                              hipStream_t stream)
{
    const float* in    = (const float*)d_in[0];
    const float* W     = (const float*)d_in[1];
    const float* b     = (const float*)d_in[2];
    const float* gamma = (const float*)d_in[3];
    const float* beta  = (const float*)d_in[4];
    const int*   unq   = (const int*)d_in[5];

    float* ws    = (float*)d_ws;
    float* accum = ws + ACC_OFF;
    float* Wp    = ws + WP_OFF;
    float* bp    = ws + BP_OFF;
    unsigned int* xmax = (unsigned int*)(ws + XMAX_OFF);

    // zero moment accumulators + x_max (0 bits == +0.0f == identity for relu'd max)
    hipMemsetAsync(d_ws, 0, (size_t)(XMAX_OFF + PIL * 32) * sizeof(float), stream);

    // pass 1: input moments (each thread strides over point-quads, 4 quads typical)
    k1_moments<<<489, 256, 0, stream>>>(in, accum);
    // pass 2: fold BN stats into W', b'
    k2_finalize<<<1, 64, 0, stream>>>(accum, W, b, gamma, beta, Wp, bp);
    // pass 3: scatter-max
    const int blk = (NQUADS + 255) / 256;  // 1954
    k3_scatter<<<blk, 256, 0, stream>>>(in, unq, Wp, bp, xmax);
    // pass 4: gather + final output
    k4_out<<<blk, 256, 0, stream>>>(in, unq, Wp, bp, (const float*)xmax, (float*)d_out);
}

// Round 2
// 1437.957 us; speedup vs baseline: 2.6216x; 2.6216x over previous
//
#include <hip/hip_runtime.h>

#define NPTS    2000000
#define NQUADS  500000     // NPTS / 4
#define PIL     100000
#define BN_EPS_F 1e-3f

// d_ws float layout
#define ACC_OFF  0         // 65 floats: m[10], S[55]
#define WP_OFF   128       // 320 floats: W' (folded BN scale)
#define BP_OFF   512       // 32 floats: b'
#define XMAX_OFF 1024      // PIL*32 floats: segment max (uint-ordered fp32)

__device__ __forceinline__ constexpr int tri_idx(int j, int k) {
    // upper-triangular (j<=k) index into 55-entry array
    return j * 10 - j * (j - 1) / 2 + (k - j);
}

// ---------------- Pass 1: input moments (m[10], S[55]) ----------------
__global__ __launch_bounds__(256) void k1_moments(const float* __restrict__ in,
                                                  float* __restrict__ accum)
{
    float m[10], S[55];
#pragma unroll
    for (int i = 0; i < 10; ++i) m[i] = 0.f;
#pragma unroll
    for (int i = 0; i < 55; ++i) S[i] = 0.f;

    const int T = gridDim.x * blockDim.x;
    for (int q = blockIdx.x * blockDim.x + threadIdx.x; q < NQUADS; q += T) {
        const float4* p4 = reinterpret_cast<const float4*>(in + (size_t)q * 40);
        float xf[40];
#pragma unroll
        for (int i = 0; i < 10; ++i) {
            float4 r = p4[i];
            xf[4*i+0] = r.x; xf[4*i+1] = r.y; xf[4*i+2] = r.z; xf[4*i+3] = r.w;
        }
#pragma unroll
        for (int p = 0; p < 4; ++p) {
#pragma unroll
            for (int j = 0; j < 10; ++j) {
                float xj = xf[p*10 + j];
                m[j] += xj;
#pragma unroll
                for (int k = j; k < 10; ++k)
                    S[tri_idx(j, k)] += xj * xf[p*10 + k];
            }
        }
    }

    // wave-level butterfly reduce, one atomicAdd per wave per value
#pragma unroll
    for (int i = 0; i < 10; ++i) {
        float v = m[i];
#pragma unroll
        for (int s = 1; s < 64; s <<= 1) v += __shfl_xor(v, s, 64);
        if ((threadIdx.x & 63) == 0) atomicAdd(accum + i, v);
    }
#pragma unroll
    for (int i = 0; i < 55; ++i) {
        float v = S[i];
#pragma unroll
        for (int s = 1; s < 64; s <<= 1) v += __shfl_xor(v, s, 64);
        if ((threadIdx.x & 63) == 0) atomicAdd(accum + 10 + i, v);
    }
}

// ---------------- Pass 2: finalize BN -> folded W', b' ----------------
__global__ void k2_finalize(const float* __restrict__ accum, const float* __restrict__ W,
                            const float* __restrict__ b, const float* __restrict__ gamma,
                            const float* __restrict__ beta, float* __restrict__ Wp,
                            float* __restrict__ bp)
{
    int c = threadIdx.x;
    if (c >= 32) return;
    const float invN = 1.0f / (float)NPTS;
    float m[10], w[10];
#pragma unroll
    for (int k = 0; k < 10; ++k) m[k] = accum[k] * invN;
#pragma unroll
    for (int k = 0; k < 10; ++k) w[k] = W[c*10 + k];
    float mean = b[c];
#pragma unroll
    for (int k = 0; k < 10; ++k) mean += w[k] * m[k];
    float var = 0.f;
#pragma unroll
    for (int j = 0; j < 10; ++j) {
#pragma unroll
        for (int k = j; k < 10; ++k) {
            float Cjk = accum[10 + tri_idx(j, k)] * invN - m[j] * m[k];
            var += w[j] * w[k] * Cjk * ((j == k) ? 1.f : 2.f);
        }
    }
    float scale = gamma[c] * rsqrtf(var + BN_EPS_F);
#pragma unroll
    for (int k = 0; k < 10; ++k) Wp[c*10 + k] = w[k] * scale;
    bp[c] = (b[c] - mean) * scale + beta[c];
}

// ---------------- Pass 3: recompute x, CONDITIONAL scatter-max ----------------
// Read the pillar row with plain (cached) loads; only atomic when the candidate
// strictly beats the observed value. Monotonicity of atomicMax makes stale
// reads harmless (extra atomic, never a missed update).
__global__ __launch_bounds__(256) void k3_scatter(const float* __restrict__ in,
                                                  const int* __restrict__ unq,
                                                  const float* __restrict__ Wp,
                                                  const float* __restrict__ bp,
                                                  unsigned int* xmax)
{
    int t = blockIdx.x * blockDim.x + threadIdx.x;
    if (t >= NPTS) return;
    const float* px = in + (size_t)t * 10;
    float4 r0 = *reinterpret_cast<const float4*>(px);
    float4 r1 = *reinterpret_cast<const float4*>(px + 4);
    float2 r2 = *reinterpret_cast<const float2*>(px + 8);
    float xf[10] = { r0.x, r0.y, r0.z, r0.w, r1.x, r1.y, r1.z, r1.w, r2.x, r2.y };

    int pil = unq[t];
    unsigned int* rowu = xmax + (size_t)pil * 32;
    const float4* row4 = reinterpret_cast<const float4*>(rowu);

    // issue current-max row loads early (8 outstanding) to hide L2/L3 latency
    float4 cur[8];
#pragma unroll
    for (int cq = 0; cq < 8; ++cq) cur[cq] = row4[cq];

    float a[32];
#pragma unroll
    for (int c = 0; c < 32; ++c) {
        float acc = bp[c];
#pragma unroll
        for (int k = 0; k < 10; ++k) acc += xf[k] * Wp[c*10 + k];
        a[c] = fmaxf(acc, 0.f);
    }

#pragma unroll
    for (int cq = 0; cq < 8; ++cq) {
        if (a[cq*4+0] > cur[cq].x) atomicMax(rowu + cq*4+0, __float_as_uint(a[cq*4+0]));
        if (a[cq*4+1] > cur[cq].y) atomicMax(rowu + cq*4+1, __float_as_uint(a[cq*4+1]));
        if (a[cq*4+2] > cur[cq].z) atomicMax(rowu + cq*4+2, __float_as_uint(a[cq*4+2]));
        if (a[cq*4+3] > cur[cq].w) atomicMax(rowu + cq*4+3, __float_as_uint(a[cq*4+3]));
    }
}

// ---------------- Pass 4: recompute x, gather pillar max, write output ----------------
__global__ __launch_bounds__(256) void k4_out(const float* __restrict__ in,
                                              const int* __restrict__ unq,
                                              const float* __restrict__ Wp,
                                              const float* __restrict__ bp,
                                              const float* __restrict__ xmax,
                                              float* __restrict__ out)
{
    int t = blockIdx.x * blockDim.x + threadIdx.x;
    if (t >= NPTS) return;
    const float* px = in + (size_t)t * 10;
    float4 r0 = *reinterpret_cast<const float4*>(px);
    float4 r1 = *reinterpret_cast<const float4*>(px + 4);
    float2 r2 = *reinterpret_cast<const float2*>(px + 8);
    float xf[10] = { r0.x, r0.y, r0.z, r0.w, r1.x, r1.y, r1.z, r1.w, r2.x, r2.y };

    int pil = unq[t];
    const float4* xm4 = reinterpret_cast<const float4*>(xmax + (size_t)pil * 32);
    float4 xr[8];
#pragma unroll
    for (int cq = 0; cq < 8; ++cq) xr[cq] = xm4[cq];   // 8 outstanding row loads

    float4* o4 = reinterpret_cast<float4*>(out + (size_t)t * 32);
#pragma unroll
    for (int cq = 0; cq < 8; ++cq) {
        float a0 = bp[cq*4+0], a1 = bp[cq*4+1], a2 = bp[cq*4+2], a3 = bp[cq*4+3];
#pragma unroll
        for (int k = 0; k < 10; ++k) {
            float x = xf[k];
            a0 += x * Wp[(cq*4+0)*10 + k];
            a1 += x * Wp[(cq*4+1)*10 + k];
            a2 += x * Wp[(cq*4+2)*10 + k];
            a3 += x * Wp[(cq*4+3)*10 + k];
        }
        float4 ov;
        ov.x = (fmaxf(a0, 0.f) + xr[cq].x) * 0.5f;
        ov.y = (fmaxf(a1, 0.f) + xr[cq].y) * 0.5f;
        ov.z = (fmaxf(a2, 0.f) + xr[cq].z) * 0.5f;
        ov.w = (fmaxf(a3, 0.f) + xr[cq].w) * 0.5f;
        o4[cq] = ov;
    }
}

extern "C" void kernel_launch(void* const* d_in, const int* in_sizes, int n_in,
                              void* d_out, int out_size, void* d_ws, size_t ws_size,
                              hipStream_t stream)
{
    const float* in    = (const float*)d_in[0];
    const float* W     = (const float*)d_in[1];
    const float* b     = (const float*)d_in[2];
    const float* gamma = (const float*)d_in[3];
    const float* beta  = (const float*)d_in[4];
    const int*   unq   = (const int*)d_in[5];

    float* ws    = (float*)d_ws;
    float* accum = ws + ACC_OFF;
    float* Wp    = ws + WP_OFF;
    float* bp    = ws + BP_OFF;
    unsigned int* xmax = (unsigned int*)(ws + XMAX_OFF);

    // zero moment accumulators + x_max (0 bits == +0.0f == identity for relu'd max)
    hipMemsetAsync(d_ws, 0, (size_t)(XMAX_OFF + PIL * 32) * sizeof(float), stream);

    // pass 1: input moments
    k1_moments<<<489, 256, 0, stream>>>(in, accum);
    // pass 2: fold BN stats into W', b'
    k2_finalize<<<1, 64, 0, stream>>>(accum, W, b, gamma, beta, Wp, bp);
    // pass 3: conditional scatter-max (one point per thread)
    const int blk1 = (NPTS + 255) / 256;   // 7813
    k3_scatter<<<blk1, 256, 0, stream>>>(in, unq, Wp, bp, xmax);
    // pass 4: gather + final output (one point per thread)
    k4_out<<<blk1, 256, 0, stream>>>(in, unq, Wp, bp, (const float*)xmax, (float*)d_out);
}

// Round 3
// 669.483 us; speedup vs baseline: 5.6309x; 2.1479x over previous
//
#include <hip/hip_runtime.h>

#define NPTS    2000000
#define PIL     100000
#define BN_EPS_F 1e-3f
#define NB1     1024       // blocks per role in pass 1

// d_ws float layout
#define ACC_OFF  0                     // 65 floats: m[10], S[55] (final reduced)
#define WP_OFF   128                   // 320 floats: W' (folded BN scale)
#define BP_OFF   512                   // 32 floats: b'
#define PART_OFF 1024                  // 65 * NB1 floats: per-block partials
#define XMAX_OFF (PART_OFF + 65*NB1 + 512)   // PIL*32 floats: segment max

__device__ __forceinline__ constexpr int tri_idx(int j, int k) {
    return j * 10 - j * (j - 1) / 2 + (k - j);
}

// accum-entry maps: acc[i] -> global accum index (m in [0,10), S in [10,65))
__device__ const int EMAP0[35] = {
    0,1,2,8,9,
    10,11,12,13,14,15,16,17,18,19,   // j=0, k=0..9
    20,21,22,23,24,25,26,27,28,      // j=1, k=1..9
    29,30,31,32,33,34,35,36,         // j=2, k=2..9
    62,63,                           // j=8, k=8..9
    64                               // j=9, k=9
};
__device__ const int EMAP1[30] = {
    3,4,5,6,7,
    37,38,39,40,41,42,43,            // j=3, k=3..9
    44,45,46,47,48,49,               // j=4, k=4..9
    50,51,52,53,54,                  // j=5, k=5..9
    55,56,57,58,                     // j=6, k=6..9
    59,60,61                         // j=7, k=7..9
};

// ---------------- Pass 1: input moments, role-split, no atomics ----------------
template<int ROLE>
__global__ __launch_bounds__(256) void k1_mom(const float* __restrict__ in,
                                              float* __restrict__ partial)
{
    constexpr int NACC = ROLE ? 30 : 35;
    float acc[NACC];
#pragma unroll
    for (int i = 0; i < NACC; ++i) acc[i] = 0.f;

    const int T = NB1 * 256;
    for (int t = blockIdx.x * 256 + threadIdx.x; t < NPTS; t += T) {
        const float* px = in + (size_t)t * 10;
        float4 r0 = *reinterpret_cast<const float4*>(px);
        float4 r1 = *reinterpret_cast<const float4*>(px + 4);
        float2 r2 = *reinterpret_cast<const float2*>(px + 8);
        float xf[10] = { r0.x, r0.y, r0.z, r0.w, r1.x, r1.y, r1.z, r1.w, r2.x, r2.y };

        if constexpr (ROLE == 0) {
            acc[0] += xf[0]; acc[1] += xf[1]; acc[2] += xf[2];
            acc[3] += xf[8]; acc[4] += xf[9];
            int o = 5;
#pragma unroll
            for (int k = 0; k < 10; ++k) acc[o++] += xf[0] * xf[k];
#pragma unroll
            for (int k = 1; k < 10; ++k) acc[o++] += xf[1] * xf[k];
#pragma unroll
            for (int k = 2; k < 10; ++k) acc[o++] += xf[2] * xf[k];
#pragma unroll
            for (int k = 8; k < 10; ++k) acc[o++] += xf[8] * xf[k];
            acc[34] += xf[9] * xf[9];
        } else {
            acc[0] += xf[3]; acc[1] += xf[4]; acc[2] += xf[5];
            acc[3] += xf[6]; acc[4] += xf[7];
            int o = 5;
#pragma unroll
            for (int k = 3; k < 10; ++k) acc[o++] += xf[3] * xf[k];
#pragma unroll
            for (int k = 4; k < 10; ++k) acc[o++] += xf[4] * xf[k];
#pragma unroll
            for (int k = 5; k < 10; ++k) acc[o++] += xf[5] * xf[k];
#pragma unroll
            for (int k = 6; k < 10; ++k) acc[o++] += xf[6] * xf[k];
#pragma unroll
            for (int k = 7; k < 10; ++k) acc[o++] += xf[7] * xf[k];
        }
    }

    // wave butterfly
#pragma unroll
    for (int i = 0; i < NACC; ++i) {
        float v = acc[i];
#pragma unroll
        for (int s = 1; s < 64; s <<= 1) v += __shfl_xor(v, s, 64);
        acc[i] = v;
    }

    // cross-wave via LDS, then ONE plain store per entry per block
    __shared__ float lds[4][36];
    const int wid = threadIdx.x >> 6, lane = threadIdx.x & 63;
    if (lane == 0) {
#pragma unroll
        for (int i = 0; i < NACC; ++i) lds[wid][i] = acc[i];
    }
    __syncthreads();
    if (threadIdx.x < NACC) {
        float s = lds[0][threadIdx.x] + lds[1][threadIdx.x]
                + lds[2][threadIdx.x] + lds[3][threadIdx.x];
        int e = (ROLE ? EMAP1 : EMAP0)[threadIdx.x];
        partial[(size_t)e * NB1 + blockIdx.x] = s;
    }
}

// ---------------- Pass 1f: reduce partials -> accum[65] ----------------
__global__ void k1_final(const float* __restrict__ partial, float* __restrict__ accum)
{
    const int e = blockIdx.x;          // 0..64
    const int lane = threadIdx.x;      // 64 threads
    float s = 0.f;
#pragma unroll
    for (int i = 0; i < NB1 / 64; ++i) s += partial[(size_t)e * NB1 + i * 64 + lane];
#pragma unroll
    for (int sh = 1; sh < 64; sh <<= 1) s += __shfl_xor(s, sh, 64);
    if (lane == 0) accum[e] = s;
}

// ---------------- Pass 2: finalize BN -> folded W', b' ----------------
__global__ void k2_finalize(const float* __restrict__ accum, const float* __restrict__ W,
                            const float* __restrict__ b, const float* __restrict__ gamma,
                            const float* __restrict__ beta, float* __restrict__ Wp,
                            float* __restrict__ bp)
{
    int c = threadIdx.x;
    if (c >= 32) return;
    const float invN = 1.0f / (float)NPTS;
    float m[10], w[10];
#pragma unroll
    for (int k = 0; k < 10; ++k) m[k] = accum[k] * invN;
#pragma unroll
    for (int k = 0; k < 10; ++k) w[k] = W[c*10 + k];
    float mean = b[c];
#pragma unroll
    for (int k = 0; k < 10; ++k) mean += w[k] * m[k];
    float var = 0.f;
#pragma unroll
    for (int j = 0; j < 10; ++j) {
#pragma unroll
        for (int k = j; k < 10; ++k) {
            float Cjk = accum[10 + tri_idx(j, k)] * invN - m[j] * m[k];
            var += w[j] * w[k] * Cjk * ((j == k) ? 1.f : 2.f);
        }
    }
    float scale = gamma[c] * rsqrtf(var + BN_EPS_F);
#pragma unroll
    for (int k = 0; k < 10; ++k) Wp[c*10 + k] = w[k] * scale;
    bp[c] = (b[c] - mean) * scale + beta[c];
}

// ---------------- Pass 3: recompute x, CONDITIONAL scatter-max ----------------
__global__ __launch_bounds__(256) void k3_scatter(const float* __restrict__ in,
                                                  const int* __restrict__ unq,
                                                  const float* __restrict__ Wp,
                                                  const float* __restrict__ bp,
                                                  unsigned int* xmax)
{
    int t = blockIdx.x * blockDim.x + threadIdx.x;
    if (t >= NPTS) return;
    const float* px = in + (size_t)t * 10;
    float4 r0 = *reinterpret_cast<const float4*>(px);
    float4 r1 = *reinterpret_cast<const float4*>(px + 4);
    float2 r2 = *reinterpret_cast<const float2*>(px + 8);
    float xf[10] = { r0.x, r0.y, r0.z, r0.w, r1.x, r1.y, r1.z, r1.w, r2.x, r2.y };

    int pil = unq[t];
    unsigned int* rowu = xmax + (size_t)pil * 32;
    const float4* row4 = reinterpret_cast<const float4*>(rowu);

    float4 cur[8];
#pragma unroll
    for (int cq = 0; cq < 8; ++cq) cur[cq] = row4[cq];

    float a[32];
#pragma unroll
    for (int c = 0; c < 32; ++c) {
        float acc = bp[c];
#pragma unroll
        for (int k = 0; k < 10; ++k) acc += xf[k] * Wp[c*10 + k];
        a[c] = fmaxf(acc, 0.f);
    }

#pragma unroll
    for (int cq = 0; cq < 8; ++cq) {
        if (a[cq*4+0] > cur[cq].x) atomicMax(rowu + cq*4+0, __float_as_uint(a[cq*4+0]));
        if (a[cq*4+1] > cur[cq].y) atomicMax(rowu + cq*4+1, __float_as_uint(a[cq*4+1]));
        if (a[cq*4+2] > cur[cq].z) atomicMax(rowu + cq*4+2, __float_as_uint(a[cq*4+2]));
        if (a[cq*4+3] > cur[cq].w) atomicMax(rowu + cq*4+3, __float_as_uint(a[cq*4+3]));
    }
}

// ---------------- Pass 4: recompute x, gather pillar max, write output ----------------
__global__ __launch_bounds__(256) void k4_out(const float* __restrict__ in,
                                              const int* __restrict__ unq,
                                              const float* __restrict__ Wp,
                                              const float* __restrict__ bp,
                                              const float* __restrict__ xmax,
                                              float* __restrict__ out)
{
    int t = blockIdx.x * blockDim.x + threadIdx.x;
    if (t >= NPTS) return;
    const float* px = in + (size_t)t * 10;
    float4 r0 = *reinterpret_cast<const float4*>(px);
    float4 r1 = *reinterpret_cast<const float4*>(px + 4);
    float2 r2 = *reinterpret_cast<const float2*>(px + 8);
    float xf[10] = { r0.x, r0.y, r0.z, r0.w, r1.x, r1.y, r1.z, r1.w, r2.x, r2.y };

    int pil = unq[t];
    const float4* xm4 = reinterpret_cast<const float4*>(xmax + (size_t)pil * 32);
    float4 xr[8];
#pragma unroll
    for (int cq = 0; cq < 8; ++cq) xr[cq] = xm4[cq];

    float4* o4 = reinterpret_cast<float4*>(out + (size_t)t * 32);
#pragma unroll
    for (int cq = 0; cq < 8; ++cq) {
        float a0 = bp[cq*4+0], a1 = bp[cq*4+1], a2 = bp[cq*4+2], a3 = bp[cq*4+3];
#pragma unroll
        for (int k = 0; k < 10; ++k) {
            float x = xf[k];
            a0 += x * Wp[(cq*4+0)*10 + k];
            a1 += x * Wp[(cq*4+1)*10 + k];
            a2 += x * Wp[(cq*4+2)*10 + k];
            a3 += x * Wp[(cq*4+3)*10 + k];
        }
        float4 ov;
        ov.x = (fmaxf(a0, 0.f) + xr[cq].x) * 0.5f;
        ov.y = (fmaxf(a1, 0.f) + xr[cq].y) * 0.5f;
        ov.z = (fmaxf(a2, 0.f) + xr[cq].z) * 0.5f;
        ov.w = (fmaxf(a3, 0.f) + xr[cq].w) * 0.5f;
        o4[cq] = ov;
    }
}

extern "C" void kernel_launch(void* const* d_in, const int* in_sizes, int n_in,
                              void* d_out, int out_size, void* d_ws, size_t ws_size,
                              hipStream_t stream)
{
    const float* in    = (const float*)d_in[0];
    const float* W     = (const float*)d_in[1];
    const float* b     = (const float*)d_in[2];
    const float* gamma = (const float*)d_in[3];
    const float* beta  = (const float*)d_in[4];
    const int*   unq   = (const int*)d_in[5];

    float* ws      = (float*)d_ws;
    float* accum   = ws + ACC_OFF;
    float* Wp      = ws + WP_OFF;
    float* bp      = ws + BP_OFF;
    float* partial = ws + PART_OFF;
    unsigned int* xmax = (unsigned int*)(ws + XMAX_OFF);

    // zero only x_max (0 bits == +0.0f == identity for relu'd max)
    hipMemsetAsync(xmax, 0, (size_t)PIL * 32 * sizeof(float), stream);

    // pass 1: input moments, role-split, atomic-free
    k1_mom<0><<<NB1, 256, 0, stream>>>(in, partial);
    k1_mom<1><<<NB1, 256, 0, stream>>>(in, partial);
    k1_final<<<65, 64, 0, stream>>>(partial, accum);
    // pass 2: fold BN stats into W', b'
    k2_finalize<<<1, 64, 0, stream>>>(accum, W, b, gamma, beta, Wp, bp);
    // pass 3: conditional scatter-max (one point per thread)
    const int blk1 = (NPTS + 255) / 256;   // 7813
    k3_scatter<<<blk1, 256, 0, stream>>>(in, unq, Wp, bp, xmax);
    // pass 4: gather + final output (one point per thread)
    k4_out<<<blk1, 256, 0, stream>>>(in, unq, Wp, bp, (const float*)xmax, (float*)d_out);
}

// Round 4
// 452.929 us; speedup vs baseline: 8.3231x; 1.4781x over previous
//
#include <hip/hip_runtime.h>

#define NPTS    2000000
#define PIL     100000
#define BN_EPS_F 1e-3f
#define NB1     1024       // blocks per role in pass 1

// counting-sort params
#define SHIFT   7
#define PPB     128                 // pillars per bucket
#define NBKT    782                 // ceil(PIL / PPB)
#define NBAC    512                 // blocks for hist/scatter passes
#define CHUNK   3907                // ceil(NPTS / NBAC)

// d_ws float/uint offsets
#define ACC_OFF  0                  // 65 f
#define WP_OFF   128                // 320 f
#define BP_OFF   512                // 32 f
#define PART_OFF 1024               // 65*NB1 f  (end 67584)
#define HIST_OFF 68096              // NBAC*NBKT u32 (end 468480)
#define OFF_OFF  468992             // NBAC*NBKT u32 (end 869376)
#define SORT_OFF 869888             // NPTS u32 (end 2869888 ~= 11.0 MiB)

__device__ __forceinline__ constexpr int tri_idx(int j, int k) {
    return j * 10 - j * (j - 1) / 2 + (k - j);
}

// accum-entry maps: acc[i] -> global accum index (m in [0,10), S in [10,65))
__device__ const int EMAP0[35] = {
    0,1,2,8,9,
    10,11,12,13,14,15,16,17,18,19,
    20,21,22,23,24,25,26,27,28,
    29,30,31,32,33,34,35,36,
    62,63,
    64
};
__device__ const int EMAP1[30] = {
    3,4,5,6,7,
    37,38,39,40,41,42,43,
    44,45,46,47,48,49,
    50,51,52,53,54,
    55,56,57,58,
    59,60,61
};

// ---------------- Pass 1: input moments, role-split, no atomics ----------------
template<int ROLE>
__global__ __launch_bounds__(256) void k1_mom(const float* __restrict__ in,
                                              float* __restrict__ partial)
{
    constexpr int NACC = ROLE ? 30 : 35;
    float acc[NACC];
#pragma unroll
    for (int i = 0; i < NACC; ++i) acc[i] = 0.f;

    const int T = NB1 * 256;
    for (int t = blockIdx.x * 256 + threadIdx.x; t < NPTS; t += T) {
        const float* px = in + (size_t)t * 10;
        float4 r0 = *reinterpret_cast<const float4*>(px);
        float4 r1 = *reinterpret_cast<const float4*>(px + 4);
        float2 r2 = *reinterpret_cast<const float2*>(px + 8);
        float xf[10] = { r0.x, r0.y, r0.z, r0.w, r1.x, r1.y, r1.z, r1.w, r2.x, r2.y };

        if constexpr (ROLE == 0) {
            acc[0] += xf[0]; acc[1] += xf[1]; acc[2] += xf[2];
            acc[3] += xf[8]; acc[4] += xf[9];
            int o = 5;
#pragma unroll
            for (int k = 0; k < 10; ++k) acc[o++] += xf[0] * xf[k];
#pragma unroll
            for (int k = 1; k < 10; ++k) acc[o++] += xf[1] * xf[k];
#pragma unroll
            for (int k = 2; k < 10; ++k) acc[o++] += xf[2] * xf[k];
#pragma unroll
            for (int k = 8; k < 10; ++k) acc[o++] += xf[8] * xf[k];
            acc[34] += xf[9] * xf[9];
        } else {
            acc[0] += xf[3]; acc[1] += xf[4]; acc[2] += xf[5];
            acc[3] += xf[6]; acc[4] += xf[7];
            int o = 5;
#pragma unroll
            for (int k = 3; k < 10; ++k) acc[o++] += xf[3] * xf[k];
#pragma unroll
            for (int k = 4; k < 10; ++k) acc[o++] += xf[4] * xf[k];
#pragma unroll
            for (int k = 5; k < 10; ++k) acc[o++] += xf[5] * xf[k];
#pragma unroll
            for (int k = 6; k < 10; ++k) acc[o++] += xf[6] * xf[k];
#pragma unroll
            for (int k = 7; k < 10; ++k) acc[o++] += xf[7] * xf[k];
        }
    }

#pragma unroll
    for (int i = 0; i < NACC; ++i) {
        float v = acc[i];
#pragma unroll
        for (int s = 1; s < 64; s <<= 1) v += __shfl_xor(v, s, 64);
        acc[i] = v;
    }

    __shared__ float lds[4][36];
    const int wid = threadIdx.x >> 6, lane = threadIdx.x & 63;
    if (lane == 0) {
#pragma unroll
        for (int i = 0; i < NACC; ++i) lds[wid][i] = acc[i];
    }
    __syncthreads();
    if (threadIdx.x < NACC) {
        float s = lds[0][threadIdx.x] + lds[1][threadIdx.x]
                + lds[2][threadIdx.x] + lds[3][threadIdx.x];
        int e = (ROLE ? EMAP1 : EMAP0)[threadIdx.x];
        partial[(size_t)e * NB1 + blockIdx.x] = s;
    }
}

// ---------------- Pass 1f: reduce partials -> accum[65] ----------------
__global__ void k1_final(const float* __restrict__ partial, float* __restrict__ accum)
{
    const int e = blockIdx.x;
    const int lane = threadIdx.x;
    float s = 0.f;
#pragma unroll
    for (int i = 0; i < NB1 / 64; ++i) s += partial[(size_t)e * NB1 + i * 64 + lane];
#pragma unroll
    for (int sh = 1; sh < 64; sh <<= 1) s += __shfl_xor(s, sh, 64);
    if (lane == 0) accum[e] = s;
}

// ---------------- Pass 2: finalize BN -> folded W', b' ----------------
__global__ void k2_finalize(const float* __restrict__ accum, const float* __restrict__ W,
                            const float* __restrict__ b, const float* __restrict__ gamma,
                            const float* __restrict__ beta, float* __restrict__ Wp,
                            float* __restrict__ bp)
{
    int c = threadIdx.x;
    if (c >= 32) return;
    const float invN = 1.0f / (float)NPTS;
    float m[10], w[10];
#pragma unroll
    for (int k = 0; k < 10; ++k) m[k] = accum[k] * invN;
#pragma unroll
    for (int k = 0; k < 10; ++k) w[k] = W[c*10 + k];
    float mean = b[c];
#pragma unroll
    for (int k = 0; k < 10; ++k) mean += w[k] * m[k];
    float var = 0.f;
#pragma unroll
    for (int j = 0; j < 10; ++j) {
#pragma unroll
        for (int k = j; k < 10; ++k) {
            float Cjk = accum[10 + tri_idx(j, k)] * invN - m[j] * m[k];
            var += w[j] * w[k] * Cjk * ((j == k) ? 1.f : 2.f);
        }
    }
    float scale = gamma[c] * rsqrtf(var + BN_EPS_F);
#pragma unroll
    for (int k = 0; k < 10; ++k) Wp[c*10 + k] = w[k] * scale;
    bp[c] = (b[c] - mean) * scale + beta[c];
}

// ---------------- kA: per-block bucket histogram (no global atomics) ----------------
__global__ __launch_bounds__(256) void kA_hist(const int* __restrict__ unq,
                                               unsigned* __restrict__ hist)
{
    __shared__ unsigned h[NBKT];
    for (int i = threadIdx.x; i < NBKT; i += 256) h[i] = 0u;
    __syncthreads();
    const int lo = blockIdx.x * CHUNK;
    const int hi = min(lo + CHUNK, NPTS);
    for (int t = lo + threadIdx.x; t < hi; t += 256)
        atomicAdd(&h[unq[t] >> SHIFT], 1u);
    __syncthreads();
    for (int i = threadIdx.x; i < NBKT; i += 256)
        hist[(size_t)blockIdx.x * NBKT + i] = h[i];
}

// ---------------- kB: bucket starts + per-(block,bucket) offsets ----------------
__global__ __launch_bounds__(1024) void kB_offsets(const unsigned* __restrict__ hist,
                                                   unsigned* __restrict__ off)
{
    __shared__ unsigned tot[1024];
    const int t = threadIdx.x;
    unsigned mine = 0;
    if (t < NBKT)
        for (int b = 0; b < NBAC; ++b) mine += hist[(size_t)b * NBKT + t];
    tot[t] = mine;
    __syncthreads();
    // Hillis-Steele inclusive scan over 1024 (NBKT padded with zeros)
    for (int d = 1; d < 1024; d <<= 1) {
        unsigned v = (t >= d) ? tot[t - d] : 0u;
        __syncthreads();
        tot[t] += v;
        __syncthreads();
    }
    if (t < NBKT) {
        unsigned run = tot[t] - mine;   // exclusive start of bucket t
        for (int b = 0; b < NBAC; ++b) {
            unsigned hv = hist[(size_t)b * NBKT + t];
            off[(size_t)b * NBKT + t] = run;
            run += hv;
        }
    }
}

// ---------------- kC: scatter packed (pil_local, idx) into bucket order ----------------
__global__ __launch_bounds__(256) void kC_scatter(const int* __restrict__ unq,
                                                  const unsigned* __restrict__ off,
                                                  unsigned* __restrict__ sorted)
{
    __shared__ unsigned cur[NBKT];
    for (int i = threadIdx.x; i < NBKT; i += 256)
        cur[i] = off[(size_t)blockIdx.x * NBKT + i];
    __syncthreads();
    const int lo = blockIdx.x * CHUNK;
    const int hi = min(lo + CHUNK, NPTS);
    for (int t = lo + threadIdx.x; t < hi; t += 256) {
        int pil = unq[t];
        unsigned slot = atomicAdd(&cur[pil >> SHIFT], 1u);
        sorted[slot] = ((unsigned)(pil & (PPB - 1)) << 21) | (unsigned)t;
    }
}

// ---------------- kD: per-bucket LDS max + fused output ----------------
__global__ __launch_bounds__(256) void kD_reduce(const float* __restrict__ in,
                                                 const unsigned* __restrict__ off,
                                                 const unsigned* __restrict__ sorted,
                                                 const float* __restrict__ Wp,
                                                 const float* __restrict__ bp,
                                                 float* __restrict__ out)
{
    __shared__ unsigned tab[PPB * 32];   // 16 KB; column swizzled by c^(pl&31)
    for (int i = threadIdx.x; i < PPB * 32; i += 256) tab[i] = 0u;
    __syncthreads();

    const unsigned bkt = blockIdx.x;
    const unsigned s0 = off[bkt];                                  // block-0 row == bucket starts
    const unsigned s1 = (bkt + 1 < NBKT) ? off[bkt + 1] : NPTS;

    // phase 1: max into LDS table
    for (unsigned pos = s0 + threadIdx.x; pos < s1; pos += 256) {
        unsigned u = sorted[pos];
        unsigned idx = u & 0x1FFFFFu;
        unsigned pl  = u >> 21;
        const float* px = in + (size_t)idx * 10;
        float4 r0 = *reinterpret_cast<const float4*>(px);
        float4 r1 = *reinterpret_cast<const float4*>(px + 4);
        float2 r2 = *reinterpret_cast<const float2*>(px + 8);
        float xf[10] = { r0.x, r0.y, r0.z, r0.w, r1.x, r1.y, r1.z, r1.w, r2.x, r2.y };
        const unsigned rowb = pl << 5, sw = pl & 31u;
#pragma unroll
        for (int c = 0; c < 32; ++c) {
            float a = bp[c];
#pragma unroll
            for (int k = 0; k < 10; ++k) a += xf[k] * Wp[c*10 + k];
            a = fmaxf(a, 0.f);
            atomicMax(&tab[rowb | ((unsigned)c ^ sw)], __float_as_uint(a));
        }
    }
    __syncthreads();

    // phase 2: recompute (bit-identical), combine with finished table, write out
    for (unsigned pos = s0 + threadIdx.x; pos < s1; pos += 256) {
        unsigned u = sorted[pos];
        unsigned idx = u & 0x1FFFFFu;
        unsigned pl  = u >> 21;
        const float* px = in + (size_t)idx * 10;
        float4 r0 = *reinterpret_cast<const float4*>(px);
        float4 r1 = *reinterpret_cast<const float4*>(px + 4);
        float2 r2 = *reinterpret_cast<const float2*>(px + 8);
        float xf[10] = { r0.x, r0.y, r0.z, r0.w, r1.x, r1.y, r1.z, r1.w, r2.x, r2.y };
        const unsigned rowb = pl << 5, sw = pl & 31u;
        float ov[32];
#pragma unroll
        for (int c = 0; c < 32; ++c) {
            float a = bp[c];
#pragma unroll
            for (int k = 0; k < 10; ++k) a += xf[k] * Wp[c*10 + k];
            a = fmaxf(a, 0.f);
            float mx = __uint_as_float(tab[rowb | ((unsigned)c ^ sw)]);
            ov[c] = (a + mx) * 0.5f;
        }
        float4* o4 = reinterpret_cast<float4*>(out + (size_t)idx * 32);
#pragma unroll
        for (int q = 0; q < 8; ++q)
            o4[q] = make_float4(ov[4*q+0], ov[4*q+1], ov[4*q+2], ov[4*q+3]);
    }
}

extern "C" void kernel_launch(void* const* d_in, const int* in_sizes, int n_in,
                              void* d_out, int out_size, void* d_ws, size_t ws_size,
                              hipStream_t stream)
{
    const float* in    = (const float*)d_in[0];
    const float* W     = (const float*)d_in[1];
    const float* b     = (const float*)d_in[2];
    const float* gamma = (const float*)d_in[3];
    const float* beta  = (const float*)d_in[4];
    const int*   unq   = (const int*)d_in[5];

    float* ws      = (float*)d_ws;
    float* accum   = ws + ACC_OFF;
    float* Wp      = ws + WP_OFF;
    float* bp      = ws + BP_OFF;
    float* partial = ws + PART_OFF;
    unsigned* hist   = (unsigned*)(ws + HIST_OFF);
    unsigned* off    = (unsigned*)(ws + OFF_OFF);
    unsigned* sorted = (unsigned*)(ws + SORT_OFF);

    // BN-stats path (atomic-free)
    k1_mom<0><<<NB1, 256, 0, stream>>>(in, partial);
    k1_mom<1><<<NB1, 256, 0, stream>>>(in, partial);
    k1_final<<<65, 64, 0, stream>>>(partial, accum);
    k2_finalize<<<1, 64, 0, stream>>>(accum, W, b, gamma, beta, Wp, bp);

    // counting sort by pillar bucket (all buffers fully overwritten; no memset needed)
    kA_hist<<<NBAC, 256, 0, stream>>>(unq, hist);
    kB_offsets<<<1, 1024, 0, stream>>>(hist, off);
    kC_scatter<<<NBAC, 256, 0, stream>>>(unq, off, sorted);

    // per-bucket LDS segment-max + fused gather/output
    kD_reduce<<<NBKT, 256, 0, stream>>>(in, off, sorted, Wp, bp, (float*)d_out);
}

// Round 5
// 434.698 us; speedup vs baseline: 8.6722x; 1.0419x over previous
//
#include <hip/hip_runtime.h>

#define NPTS    2000000
#define PIL     100000
#define BN_EPS_F 1e-3f

// counting-sort params
#define SHIFT   7
#define PPB     128                 // pillars per bucket
#define NBKT    782                 // ceil(PIL / PPB)
#define NBAC    512                 // blocks for hist/scatter passes
#define CHUNK   3907                // ceil(NPTS / NBAC)
#define NB      512                 // blocks per role in moment pass

// d_ws float-index offsets
#define ACC_OFF   0                 // 65 f
#define WP_OFF    128               // 320 f
#define BP_OFF    512               // 32 f
#define PART_OFF  1024              // 65*NB f (end 34,304)
#define HIST_OFF  34816             // NBAC*NBKT u32 (end 435,200)
#define OFF_OFF   435712            // NBAC*NBKT u32 (end 836,096)
#define TOTS_OFF  836608            // NBKT u32
#define STARTS_OFF 837632           // NBKT+1 u32
#define PS_OFF    839680            // NPTS*12 f (data-sort path) OR NPTS u32 (fallback)
#define REQ_BYTES ((size_t)(PS_OFF + (size_t)NPTS * 12) * 4)

__device__ __forceinline__ constexpr int tri_idx(int j, int k) {
    return j * 10 - j * (j - 1) / 2 + (k - j);
}

__device__ const int EMAP0[35] = {
    0,1,2,8,9,
    10,11,12,13,14,15,16,17,18,19,
    20,21,22,23,24,25,26,27,28,
    29,30,31,32,33,34,35,36,
    62,63,
    64
};
__device__ const int EMAP1[30] = {
    3,4,5,6,7,
    37,38,39,40,41,42,43,
    44,45,46,47,48,49,
    50,51,52,53,54,
    55,56,57,58,
    59,60,61
};

__device__ __forceinline__ void load_row(const float* __restrict__ px, float* xf) {
    float4 r0 = *reinterpret_cast<const float4*>(px);
    float4 r1 = *reinterpret_cast<const float4*>(px + 4);
    float2 r2 = *reinterpret_cast<const float2*>(px + 8);
    xf[0]=r0.x; xf[1]=r0.y; xf[2]=r0.z; xf[3]=r0.w;
    xf[4]=r1.x; xf[5]=r1.y; xf[6]=r1.z; xf[7]=r1.w;
    xf[8]=r2.x; xf[9]=r2.y;
}

// ---------------- kA: bucket histogram + role-0 moments (fused) ----------------
__global__ __launch_bounds__(256) void kA_hist_mom(const float* __restrict__ in,
                                                   const int* __restrict__ unq,
                                                   unsigned* __restrict__ hist,
                                                   float* __restrict__ partial)
{
    __shared__ unsigned h[NBKT];
    __shared__ float lds2[4][36];
    for (int i = threadIdx.x; i < NBKT; i += 256) h[i] = 0u;
    __syncthreads();

    float acc[35];
#pragma unroll
    for (int i = 0; i < 35; ++i) acc[i] = 0.f;

    const int lo = blockIdx.x * CHUNK;
    const int hi = min(lo + CHUNK, NPTS);
    for (int t = lo + threadIdx.x; t < hi; t += 256) {
        atomicAdd(&h[unq[t] >> SHIFT], 1u);
        float xf[10];
        load_row(in + (size_t)t * 10, xf);
        acc[0] += xf[0]; acc[1] += xf[1]; acc[2] += xf[2];
        acc[3] += xf[8]; acc[4] += xf[9];
        int o = 5;
#pragma unroll
        for (int k = 0; k < 10; ++k) acc[o++] += xf[0] * xf[k];
#pragma unroll
        for (int k = 1; k < 10; ++k) acc[o++] += xf[1] * xf[k];
#pragma unroll
        for (int k = 2; k < 10; ++k) acc[o++] += xf[2] * xf[k];
#pragma unroll
        for (int k = 8; k < 10; ++k) acc[o++] += xf[8] * xf[k];
        acc[34] += xf[9] * xf[9];
    }
    __syncthreads();
    for (int i = threadIdx.x; i < NBKT; i += 256)
        hist[(size_t)blockIdx.x * NBKT + i] = h[i];

#pragma unroll
    for (int i = 0; i < 35; ++i) {
        float v = acc[i];
#pragma unroll
        for (int s = 1; s < 64; s <<= 1) v += __shfl_xor(v, s, 64);
        acc[i] = v;
    }
    const int wid = threadIdx.x >> 6, lane = threadIdx.x & 63;
    if (lane == 0) {
#pragma unroll
        for (int i = 0; i < 35; ++i) lds2[wid][i] = acc[i];
    }
    __syncthreads();
    if (threadIdx.x < 35) {
        float s = lds2[0][threadIdx.x] + lds2[1][threadIdx.x]
                + lds2[2][threadIdx.x] + lds2[3][threadIdx.x];
        partial[(size_t)EMAP0[threadIdx.x] * NB + blockIdx.x] = s;
    }
}

// ---------------- k1b: role-1 moments ----------------
__global__ __launch_bounds__(256) void k1_mom1(const float* __restrict__ in,
                                               float* __restrict__ partial)
{
    float acc[30];
#pragma unroll
    for (int i = 0; i < 30; ++i) acc[i] = 0.f;
    const int T = NB * 256;
    for (int t = blockIdx.x * 256 + threadIdx.x; t < NPTS; t += T) {
        float xf[10];
        load_row(in + (size_t)t * 10, xf);
        acc[0] += xf[3]; acc[1] += xf[4]; acc[2] += xf[5];
        acc[3] += xf[6]; acc[4] += xf[7];
        int o = 5;
#pragma unroll
        for (int k = 3; k < 10; ++k) acc[o++] += xf[3] * xf[k];
#pragma unroll
        for (int k = 4; k < 10; ++k) acc[o++] += xf[4] * xf[k];
#pragma unroll
        for (int k = 5; k < 10; ++k) acc[o++] += xf[5] * xf[k];
#pragma unroll
        for (int k = 6; k < 10; ++k) acc[o++] += xf[6] * xf[k];
#pragma unroll
        for (int k = 7; k < 10; ++k) acc[o++] += xf[7] * xf[k];
    }
#pragma unroll
    for (int i = 0; i < 30; ++i) {
        float v = acc[i];
#pragma unroll
        for (int s = 1; s < 64; s <<= 1) v += __shfl_xor(v, s, 64);
        acc[i] = v;
    }
    __shared__ float lds2[4][36];
    const int wid = threadIdx.x >> 6, lane = threadIdx.x & 63;
    if (lane == 0) {
#pragma unroll
        for (int i = 0; i < 30; ++i) lds2[wid][i] = acc[i];
    }
    __syncthreads();
    if (threadIdx.x < 30) {
        float s = lds2[0][threadIdx.x] + lds2[1][threadIdx.x]
                + lds2[2][threadIdx.x] + lds2[3][threadIdx.x];
        partial[(size_t)EMAP1[threadIdx.x] * NB + blockIdx.x] = s;
    }
}

// ---------------- k1f: reduce partials -> accum[65] ----------------
__global__ void k1_final(const float* __restrict__ partial, float* __restrict__ accum)
{
    const int e = blockIdx.x, lane = threadIdx.x;
    float s = 0.f;
#pragma unroll
    for (int i = 0; i < NB / 64; ++i) s += partial[(size_t)e * NB + i * 64 + lane];
#pragma unroll
    for (int sh = 1; sh < 64; sh <<= 1) s += __shfl_xor(s, sh, 64);
    if (lane == 0) accum[e] = s;
}

// ---------------- k2: finalize BN -> folded W', b' ----------------
__global__ void k2_finalize(const float* __restrict__ accum, const float* __restrict__ W,
                            const float* __restrict__ b, const float* __restrict__ gamma,
                            const float* __restrict__ beta, float* __restrict__ Wp,
                            float* __restrict__ bp)
{
    int c = threadIdx.x;
    if (c >= 32) return;
    const float invN = 1.0f / (float)NPTS;
    float m[10], w[10];
#pragma unroll
    for (int k = 0; k < 10; ++k) m[k] = accum[k] * invN;
#pragma unroll
    for (int k = 0; k < 10; ++k) w[k] = W[c*10 + k];
    float mean = b[c];
#pragma unroll
    for (int k = 0; k < 10; ++k) mean += w[k] * m[k];
    float var = 0.f;
#pragma unroll
    for (int j = 0; j < 10; ++j) {
#pragma unroll
        for (int k = j; k < 10; ++k) {
            float Cjk = accum[10 + tri_idx(j, k)] * invN - m[j] * m[k];
            var += w[j] * w[k] * Cjk * ((j == k) ? 1.f : 2.f);
        }
    }
    float scale = gamma[c] * rsqrtf(var + BN_EPS_F);
#pragma unroll
    for (int k = 0; k < 10; ++k) Wp[c*10 + k] = w[k] * scale;
    bp[c] = (b[c] - mean) * scale + beta[c];
}

// ---------------- kB1: per-bucket totals ----------------
__global__ __launch_bounds__(64) void kB1_colsum(const unsigned* __restrict__ hist,
                                                 unsigned* __restrict__ tots)
{
    const int c = blockIdx.x, lane = threadIdx.x;
    unsigned s = 0;
#pragma unroll
    for (int i = 0; i < NBAC / 64; ++i) s += hist[(size_t)(i * 64 + lane) * NBKT + c];
#pragma unroll
    for (int sh = 1; sh < 64; sh <<= 1) s += __shfl_xor(s, sh, 64);
    if (lane == 0) tots[c] = s;
}

// ---------------- kB2: scan totals -> bucket starts ----------------
__global__ __launch_bounds__(1024) void kB2_scan(const unsigned* __restrict__ tots,
                                                 unsigned* __restrict__ starts)
{
    __shared__ unsigned tot[1024];
    const int t = threadIdx.x;
    unsigned mine = (t < NBKT) ? tots[t] : 0u;
    tot[t] = mine;
    __syncthreads();
    for (int d = 1; d < 1024; d <<= 1) {
        unsigned v = (t >= d) ? tot[t - d] : 0u;
        __syncthreads();
        tot[t] += v;
        __syncthreads();
    }
    if (t < NBKT) starts[t] = tot[t] - mine;
    if (t == NBKT - 1) starts[NBKT] = tot[t];
}

// ---------------- kB3: expand per-(block,bucket) offsets ----------------
__global__ __launch_bounds__(64) void kB3_expand(const unsigned* __restrict__ hist,
                                                 const unsigned* __restrict__ starts,
                                                 unsigned* __restrict__ off)
{
    const int c = blockIdx.x, lane = threadIdx.x;
    unsigned hv[NBAC / 64];
    unsigned psum = 0;
#pragma unroll
    for (int i = 0; i < NBAC / 64; ++i) {
        hv[i] = hist[(size_t)(lane * (NBAC / 64) + i) * NBKT + c];
        psum += hv[i];
    }
    unsigned incl = psum;
#pragma unroll
    for (int s = 1; s < 64; s <<= 1) {
        unsigned v = __shfl_up(incl, s, 64);
        if (lane >= s) incl += v;
    }
    unsigned run = starts[c] + (incl - psum);
#pragma unroll
    for (int i = 0; i < NBAC / 64; ++i) {
        off[(size_t)(lane * (NBAC / 64) + i) * NBKT + c] = run;
        run += hv[i];
    }
}

// ---------------- kC2: scatter FULL 48B point records into bucket order ----------------
__global__ __launch_bounds__(256) void kC2_scatter(const float* __restrict__ in,
                                                   const int* __restrict__ unq,
                                                   const unsigned* __restrict__ off,
                                                   float4* __restrict__ ps4)
{
    __shared__ unsigned cur[NBKT];
    for (int i = threadIdx.x; i < NBKT; i += 256)
        cur[i] = off[(size_t)blockIdx.x * NBKT + i];
    __syncthreads();
    const int lo = blockIdx.x * CHUNK;
    const int hi = min(lo + CHUNK, NPTS);
    for (int t = lo + threadIdx.x; t < hi; t += 256) {
        int pil = unq[t];
        unsigned slot = atomicAdd(&cur[pil >> SHIFT], 1u);
        const float* px = in + (size_t)t * 10;
        float4 r0 = *reinterpret_cast<const float4*>(px);
        float4 r1 = *reinterpret_cast<const float4*>(px + 4);
        float2 r2 = *reinterpret_cast<const float2*>(px + 8);
        unsigned meta = ((unsigned)(pil & (PPB - 1)) << 21) | (unsigned)t;
        float4* d = ps4 + (size_t)slot * 3;
        d[0] = r0;
        d[1] = r1;
        d[2] = make_float4(r2.x, r2.y, __uint_as_float(meta), 0.f);
    }
}

// ---------------- kD2: per-bucket LDS max + fused output, SEQUENTIAL reads ----------------
__global__ __launch_bounds__(256) void kD2_reduce(const float4* __restrict__ ps4,
                                                  const unsigned* __restrict__ starts,
                                                  const float* __restrict__ Wp,
                                                  const float* __restrict__ bp,
                                                  float* __restrict__ out)
{
    __shared__ unsigned tab[PPB * 32];   // 16 KB; column swizzled by c^(pl&31)
    for (int i = threadIdx.x; i < PPB * 32; i += 256) tab[i] = 0u;
    __syncthreads();

    const unsigned s0 = starts[blockIdx.x];
    const unsigned s1 = starts[blockIdx.x + 1];

    // phase 1: sequential stream, max into LDS table
    for (unsigned pos = s0 + threadIdx.x; pos < s1; pos += 256) {
        const float4* p = ps4 + (size_t)pos * 3;
        float4 v0 = p[0], v1 = p[1], v2 = p[2];
        float xf[10] = { v0.x, v0.y, v0.z, v0.w, v1.x, v1.y, v1.z, v1.w, v2.x, v2.y };
        unsigned meta = __float_as_uint(v2.z);
        unsigned pl = meta >> 21;
        const unsigned rowb = pl << 5, sw = pl & 31u;
#pragma unroll
        for (int c = 0; c < 32; ++c) {
            float a = bp[c];
#pragma unroll
            for (int k = 0; k < 10; ++k) a += xf[k] * Wp[c*10 + k];
            a = fmaxf(a, 0.f);
            atomicMax(&tab[rowb | ((unsigned)c ^ sw)], __float_as_uint(a));
        }
    }
    __syncthreads();

    // phase 2: re-stream (L2/L3-hot), bit-identical recompute, write out
    for (unsigned pos = s0 + threadIdx.x; pos < s1; pos += 256) {
        const float4* p = ps4 + (size_t)pos * 3;
        float4 v0 = p[0], v1 = p[1], v2 = p[2];
        float xf[10] = { v0.x, v0.y, v0.z, v0.w, v1.x, v1.y, v1.z, v1.w, v2.x, v2.y };
        unsigned meta = __float_as_uint(v2.z);
        unsigned idx = meta & 0x1FFFFFu;
        unsigned pl = meta >> 21;
        const unsigned rowb = pl << 5, sw = pl & 31u;
        float ov[32];
#pragma unroll
        for (int c = 0; c < 32; ++c) {
            float a = bp[c];
#pragma unroll
            for (int k = 0; k < 10; ++k) a += xf[k] * Wp[c*10 + k];
            a = fmaxf(a, 0.f);
            float mx = __uint_as_float(tab[rowb | ((unsigned)c ^ sw)]);
            ov[c] = (a + mx) * 0.5f;
        }
        float4* o4 = reinterpret_cast<float4*>(out + (size_t)idx * 32);
#pragma unroll
        for (int q = 0; q < 8; ++q)
            o4[q] = make_float4(ov[4*q+0], ov[4*q+1], ov[4*q+2], ov[4*q+3]);
    }
}

// ---------------- fallback (small ws): index sort + gather kD (R4 path) ----------------
__global__ __launch_bounds__(256) void kC_idx(const int* __restrict__ unq,
                                              const unsigned* __restrict__ off,
                                              unsigned* __restrict__ sorted)
{
    __shared__ unsigned cur[NBKT];
    for (int i = threadIdx.x; i < NBKT; i += 256)
        cur[i] = off[(size_t)blockIdx.x * NBKT + i];
    __syncthreads();
    const int lo = blockIdx.x * CHUNK;
    const int hi = min(lo + CHUNK, NPTS);
    for (int t = lo + threadIdx.x; t < hi; t += 256) {
        int pil = unq[t];
        unsigned slot = atomicAdd(&cur[pil >> SHIFT], 1u);
        sorted[slot] = ((unsigned)(pil & (PPB - 1)) << 21) | (unsigned)t;
    }
}

__global__ __launch_bounds__(256) void kD_idx(const float* __restrict__ in,
                                              const unsigned* __restrict__ starts,
                                              const unsigned* __restrict__ sorted,
                                              const float* __restrict__ Wp,
                                              const float* __restrict__ bp,
                                              float* __restrict__ out)
{
    __shared__ unsigned tab[PPB * 32];
    for (int i = threadIdx.x; i < PPB * 32; i += 256) tab[i] = 0u;
    __syncthreads();
    const unsigned s0 = starts[blockIdx.x];
    const unsigned s1 = starts[blockIdx.x + 1];
    for (unsigned pos = s0 + threadIdx.x; pos < s1; pos += 256) {
        unsigned u = sorted[pos];
        unsigned idx = u & 0x1FFFFFu, pl = u >> 21;
        float xf[10];
        load_row(in + (size_t)idx * 10, xf);
        const unsigned rowb = pl << 5, sw = pl & 31u;
#pragma unroll
        for (int c = 0; c < 32; ++c) {
            float a = bp[c];
#pragma unroll
            for (int k = 0; k < 10; ++k) a += xf[k] * Wp[c*10 + k];
            a = fmaxf(a, 0.f);
            atomicMax(&tab[rowb | ((unsigned)c ^ sw)], __float_as_uint(a));
        }
    }
    __syncthreads();
    for (unsigned pos = s0 + threadIdx.x; pos < s1; pos += 256) {
        unsigned u = sorted[pos];
        unsigned idx = u & 0x1FFFFFu, pl = u >> 21;
        float xf[10];
        load_row(in + (size_t)idx * 10, xf);
        const unsigned rowb = pl << 5, sw = pl & 31u;
        float ov[32];
#pragma unroll
        for (int c = 0; c < 32; ++c) {
            float a = bp[c];
#pragma unroll
            for (int k = 0; k < 10; ++k) a += xf[k] * Wp[c*10 + k];
            a = fmaxf(a, 0.f);
            float mx = __uint_as_float(tab[rowb | ((unsigned)c ^ sw)]);
            ov[c] = (a + mx) * 0.5f;
        }
        float4* o4 = reinterpret_cast<float4*>(out + (size_t)idx * 32);
#pragma unroll
        for (int q = 0; q < 8; ++q)
            o4[q] = make_float4(ov[4*q+0], ov[4*q+1], ov[4*q+2], ov[4*q+3]);
    }
}

extern "C" void kernel_launch(void* const* d_in, const int* in_sizes, int n_in,
                              void* d_out, int out_size, void* d_ws, size_t ws_size,
                              hipStream_t stream)
{
    const float* in    = (const float*)d_in[0];
    const float* W     = (const float*)d_in[1];
    const float* b     = (const float*)d_in[2];
    const float* gamma = (const float*)d_in[3];
    const float* beta  = (const float*)d_in[4];
    const int*   unq   = (const int*)d_in[5];

    float* ws      = (float*)d_ws;
    float* accum   = ws + ACC_OFF;
    float* Wp      = ws + WP_OFF;
    float* bp      = ws + BP_OFF;
    float* partial = ws + PART_OFF;
    unsigned* hist   = (unsigned*)(ws + HIST_OFF);
    unsigned* off    = (unsigned*)(ws + OFF_OFF);
    unsigned* tots   = (unsigned*)(ws + TOTS_OFF);
    unsigned* starts = (unsigned*)(ws + STARTS_OFF);

    // histogram + role-0 moments fused; role-1 moments in parallel pass
    kA_hist_mom<<<NBAC, 256, 0, stream>>>(in, unq, hist, partial);
    k1_mom1<<<NB, 256, 0, stream>>>(in, partial);
    // offsets
    kB1_colsum<<<NBKT, 64, 0, stream>>>(hist, tots);
    kB2_scan<<<1, 1024, 0, stream>>>(tots, starts);
    kB3_expand<<<NBKT, 64, 0, stream>>>(hist, starts, off);
    // BN fold
    k1_final<<<65, 64, 0, stream>>>(partial, accum);
    k2_finalize<<<1, 64, 0, stream>>>(accum, W, b, gamma, beta, Wp, bp);

    if (ws_size >= REQ_BYTES) {
        float4* ps4 = (float4*)(ws + PS_OFF);
        kC2_scatter<<<NBAC, 256, 0, stream>>>(in, unq, off, ps4);
        kD2_reduce<<<NBKT, 256, 0, stream>>>(ps4, starts, Wp, bp, (float*)d_out);
    } else {
        unsigned* sorted = (unsigned*)(ws + PS_OFF);
        kC_idx<<<NBAC, 256, 0, stream>>>(unq, off, sorted);
        kD_idx<<<NBKT, 256, 0, stream>>>(in, starts, sorted, Wp, bp, (float*)d_out);
    }
}

// Round 6
// 369.506 us; speedup vs baseline: 10.2023x; 1.1764x over previous
//
#include <hip/hip_runtime.h>

#define NPTS    2000000
#define PIL     100000
#define BN_EPS_F 1e-3f

// counting-sort params
#define SHIFT   6
#define PPB     64                  // pillars per bucket
#define NBKT    1563                // ceil(PIL / PPB)
#define NBAC    512                 // blocks for hist/scatter passes
#define CHUNK   3907                // ceil(NPTS / NBAC)
#define NB      512                 // blocks per role in moment pass

// d_ws float-index offsets
#define ACC_OFF    0                // 65 f
#define WP_OFF     128              // 320 f
#define BP_OFF     512              // 32 f
#define PART_OFF   1024             // 65*NB f (end 34,304)
#define HIST_OFF   34816            // NBAC*NBKT u32 (end 835,072); kB3 rewrites in place to offsets
#define TOTS_OFF   835584           // NBKT u32
#define STARTS_OFF 837632           // NBKT+1 u32
#define PS_OFF     839680           // NPTS*12 f (data-sort) OR NPTS u32 (fallback)
#define REQ_BYTES ((size_t)(PS_OFF + (size_t)NPTS * 12) * 4)

__device__ __forceinline__ constexpr int tri_idx(int j, int k) {
    return j * 10 - j * (j - 1) / 2 + (k - j);
}

__device__ const int EMAP0[35] = {
    0,1,2,8,9,
    10,11,12,13,14,15,16,17,18,19,
    20,21,22,23,24,25,26,27,28,
    29,30,31,32,33,34,35,36,
    62,63,
    64
};
__device__ const int EMAP1[30] = {
    3,4,5,6,7,
    37,38,39,40,41,42,43,
    44,45,46,47,48,49,
    50,51,52,53,54,
    55,56,57,58,
    59,60,61
};

__device__ __forceinline__ void load_row(const float* __restrict__ px, float* xf) {
    float4 r0 = *reinterpret_cast<const float4*>(px);
    float4 r1 = *reinterpret_cast<const float4*>(px + 4);
    float2 r2 = *reinterpret_cast<const float2*>(px + 8);
    xf[0]=r0.x; xf[1]=r0.y; xf[2]=r0.z; xf[3]=r0.w;
    xf[4]=r1.x; xf[5]=r1.y; xf[6]=r1.z; xf[7]=r1.w;
    xf[8]=r2.x; xf[9]=r2.y;
}

// ---------------- kA: bucket histogram + role-0 moments (fused) ----------------
__global__ __launch_bounds__(256) void kA_hist_mom(const float* __restrict__ in,
                                                   const int* __restrict__ unq,
                                                   unsigned* __restrict__ hist,
                                                   float* __restrict__ partial)
{
    __shared__ unsigned h[NBKT];
    __shared__ float lds2[4][36];
    for (int i = threadIdx.x; i < NBKT; i += 256) h[i] = 0u;
    __syncthreads();

    float acc[35];
#pragma unroll
    for (int i = 0; i < 35; ++i) acc[i] = 0.f;

    const int lo = blockIdx.x * CHUNK;
    const int hi = min(lo + CHUNK, NPTS);
    for (int t = lo + threadIdx.x; t < hi; t += 256) {
        atomicAdd(&h[unq[t] >> SHIFT], 1u);
        float xf[10];
        load_row(in + (size_t)t * 10, xf);
        acc[0] += xf[0]; acc[1] += xf[1]; acc[2] += xf[2];
        acc[3] += xf[8]; acc[4] += xf[9];
        int o = 5;
#pragma unroll
        for (int k = 0; k < 10; ++k) acc[o++] += xf[0] * xf[k];
#pragma unroll
        for (int k = 1; k < 10; ++k) acc[o++] += xf[1] * xf[k];
#pragma unroll
        for (int k = 2; k < 10; ++k) acc[o++] += xf[2] * xf[k];
#pragma unroll
        for (int k = 8; k < 10; ++k) acc[o++] += xf[8] * xf[k];
        acc[34] += xf[9] * xf[9];
    }
    __syncthreads();
    for (int i = threadIdx.x; i < NBKT; i += 256)
        hist[(size_t)blockIdx.x * NBKT + i] = h[i];

#pragma unroll
    for (int i = 0; i < 35; ++i) {
        float v = acc[i];
#pragma unroll
        for (int s = 1; s < 64; s <<= 1) v += __shfl_xor(v, s, 64);
        acc[i] = v;
    }
    const int wid = threadIdx.x >> 6, lane = threadIdx.x & 63;
    if (lane == 0) {
#pragma unroll
        for (int i = 0; i < 35; ++i) lds2[wid][i] = acc[i];
    }
    __syncthreads();
    if (threadIdx.x < 35) {
        float s = lds2[0][threadIdx.x] + lds2[1][threadIdx.x]
                + lds2[2][threadIdx.x] + lds2[3][threadIdx.x];
        partial[(size_t)EMAP0[threadIdx.x] * NB + blockIdx.x] = s;
    }
}

// ---------------- k1b: role-1 moments ----------------
__global__ __launch_bounds__(256) void k1_mom1(const float* __restrict__ in,
                                               float* __restrict__ partial)
{
    float acc[30];
#pragma unroll
    for (int i = 0; i < 30; ++i) acc[i] = 0.f;
    const int T = NB * 256;
    for (int t = blockIdx.x * 256 + threadIdx.x; t < NPTS; t += T) {
        float xf[10];
        load_row(in + (size_t)t * 10, xf);
        acc[0] += xf[3]; acc[1] += xf[4]; acc[2] += xf[5];
        acc[3] += xf[6]; acc[4] += xf[7];
        int o = 5;
#pragma unroll
        for (int k = 3; k < 10; ++k) acc[o++] += xf[3] * xf[k];
#pragma unroll
        for (int k = 4; k < 10; ++k) acc[o++] += xf[4] * xf[k];
#pragma unroll
        for (int k = 5; k < 10; ++k) acc[o++] += xf[5] * xf[k];
#pragma unroll
        for (int k = 6; k < 10; ++k) acc[o++] += xf[6] * xf[k];
#pragma unroll
        for (int k = 7; k < 10; ++k) acc[o++] += xf[7] * xf[k];
    }
#pragma unroll
    for (int i = 0; i < 30; ++i) {
        float v = acc[i];
#pragma unroll
        for (int s = 1; s < 64; s <<= 1) v += __shfl_xor(v, s, 64);
        acc[i] = v;
    }
    __shared__ float lds2[4][36];
    const int wid = threadIdx.x >> 6, lane = threadIdx.x & 63;
    if (lane == 0) {
#pragma unroll
        for (int i = 0; i < 30; ++i) lds2[wid][i] = acc[i];
    }
    __syncthreads();
    if (threadIdx.x < 30) {
        float s = lds2[0][threadIdx.x] + lds2[1][threadIdx.x]
                + lds2[2][threadIdx.x] + lds2[3][threadIdx.x];
        partial[(size_t)EMAP1[threadIdx.x] * NB + blockIdx.x] = s;
    }
}

// ---------------- k1f: reduce partials -> accum[65] ----------------
__global__ void k1_final(const float* __restrict__ partial, float* __restrict__ accum)
{
    const int e = blockIdx.x, lane = threadIdx.x;
    float s = 0.f;
#pragma unroll
    for (int i = 0; i < NB / 64; ++i) s += partial[(size_t)e * NB + i * 64 + lane];
#pragma unroll
    for (int sh = 1; sh < 64; sh <<= 1) s += __shfl_xor(s, sh, 64);
    if (lane == 0) accum[e] = s;
}

// ---------------- k2: finalize BN -> folded W', b' ----------------
__global__ void k2_finalize(const float* __restrict__ accum, const float* __restrict__ W,
                            const float* __restrict__ b, const float* __restrict__ gamma,
                            const float* __restrict__ beta, float* __restrict__ Wp,
                            float* __restrict__ bp)
{
    int c = threadIdx.x;
    if (c >= 32) return;
    const float invN = 1.0f / (float)NPTS;
    float m[10], w[10];
#pragma unroll
    for (int k = 0; k < 10; ++k) m[k] = accum[k] * invN;
#pragma unroll
    for (int k = 0; k < 10; ++k) w[k] = W[c*10 + k];
    float mean = b[c];
#pragma unroll
    for (int k = 0; k < 10; ++k) mean += w[k] * m[k];
    float var = 0.f;
#pragma unroll
    for (int j = 0; j < 10; ++j) {
#pragma unroll
        for (int k = j; k < 10; ++k) {
            float Cjk = accum[10 + tri_idx(j, k)] * invN - m[j] * m[k];
            var += w[j] * w[k] * Cjk * ((j == k) ? 1.f : 2.f);
        }
    }
    float scale = gamma[c] * rsqrtf(var + BN_EPS_F);
#pragma unroll
    for (int k = 0; k < 10; ++k) Wp[c*10 + k] = w[k] * scale;
    bp[c] = (b[c] - mean) * scale + beta[c];
}

// ---------------- kB1: per-bucket totals ----------------
__global__ __launch_bounds__(64) void kB1_colsum(const unsigned* __restrict__ hist,
                                                 unsigned* __restrict__ tots)
{
    const int c = blockIdx.x, lane = threadIdx.x;
    unsigned s = 0;
#pragma unroll
    for (int i = 0; i < NBAC / 64; ++i) s += hist[(size_t)(i * 64 + lane) * NBKT + c];
#pragma unroll
    for (int sh = 1; sh < 64; sh <<= 1) s += __shfl_xor(s, sh, 64);
    if (lane == 0) tots[c] = s;
}

// ---------------- kB2: scan totals (1563) -> bucket starts; 2 elems/thread ----------------
__global__ __launch_bounds__(1024) void kB2_scan(const unsigned* __restrict__ tots,
                                                 unsigned* __restrict__ starts)
{
    __shared__ unsigned ps[1024];
    const int t = threadIdx.x;
    unsigned v0 = (2*t     < NBKT) ? tots[2*t]     : 0u;
    unsigned v1 = (2*t + 1 < NBKT) ? tots[2*t + 1] : 0u;
    unsigned pair = v0 + v1;
    ps[t] = pair;
    __syncthreads();
    for (int d = 1; d < 1024; d <<= 1) {
        unsigned v = (t >= d) ? ps[t - d] : 0u;
        __syncthreads();
        ps[t] += v;
        __syncthreads();
    }
    unsigned excl = ps[t] - pair;
    if (2*t     < NBKT) starts[2*t]     = excl;
    if (2*t + 1 < NBKT) starts[2*t + 1] = excl + v0;
    if (t == 1023) starts[NBKT] = ps[1023];
}

// ---------------- kB3: expand per-(block,bucket) offsets IN PLACE over hist ----------------
__global__ __launch_bounds__(64) void kB3_expand(unsigned* __restrict__ hist,
                                                 const unsigned* __restrict__ starts)
{
    const int c = blockIdx.x, lane = threadIdx.x;
    unsigned hv[NBAC / 64];
    unsigned psum = 0;
#pragma unroll
    for (int i = 0; i < NBAC / 64; ++i) {
        hv[i] = hist[(size_t)(lane * (NBAC / 64) + i) * NBKT + c];
        psum += hv[i];
    }
    unsigned incl = psum;
#pragma unroll
    for (int s = 1; s < 64; s <<= 1) {
        unsigned v = __shfl_up(incl, s, 64);
        if (lane >= s) incl += v;
    }
    unsigned run = starts[c] + (incl - psum);
#pragma unroll
    for (int i = 0; i < NBAC / 64; ++i) {
        hist[(size_t)(lane * (NBAC / 64) + i) * NBKT + c] = run;
        run += hv[i];
    }
}

// ---------------- kC2: scatter FULL 48B point records into bucket order ----------------
__global__ __launch_bounds__(256) void kC2_scatter(const float* __restrict__ in,
                                                   const int* __restrict__ unq,
                                                   const unsigned* __restrict__ off,
                                                   float4* __restrict__ ps4)
{
    __shared__ unsigned cur[NBKT];
    for (int i = threadIdx.x; i < NBKT; i += 256)
        cur[i] = off[(size_t)blockIdx.x * NBKT + i];
    __syncthreads();
    const int lo = blockIdx.x * CHUNK;
    const int hi = min(lo + CHUNK, NPTS);
    for (int t = lo + threadIdx.x; t < hi; t += 256) {
        int pil = unq[t];
        unsigned slot = atomicAdd(&cur[pil >> SHIFT], 1u);
        const float* px = in + (size_t)t * 10;
        float4 r0 = *reinterpret_cast<const float4*>(px);
        float4 r1 = *reinterpret_cast<const float4*>(px + 4);
        float2 r2 = *reinterpret_cast<const float2*>(px + 8);
        unsigned meta = ((unsigned)(pil & (PPB - 1)) << 21) | (unsigned)t;
        float4* d = ps4 + (size_t)slot * 3;
        d[0] = r0;
        d[1] = r1;
        d[2] = make_float4(r2.x, r2.y, __uint_as_float(meta), 0.f);
    }
}

// ---------------- kD3: channel-per-lane per-bucket max + fused output ----------------
// lane owns channel c = tid&31 (weights in 11 registers, never reloaded);
// half-wave 0 handles point p, half-wave 1 point p+1; block covers 8 points/step.
__global__ __launch_bounds__(256) void kD3_reduce(const float4* __restrict__ ps4,
                                                  const unsigned* __restrict__ starts,
                                                  const float* __restrict__ Wp,
                                                  const float* __restrict__ bp,
                                                  float* __restrict__ out)
{
    __shared__ unsigned tab[PPB * 32];   // 8 KB; tab[pl*32 + c] -> bank c (2-way max)
    for (int i = threadIdx.x; i < PPB * 32; i += 256) tab[i] = 0u;

    const int c   = threadIdx.x & 31;
    const int sub = threadIdx.x >> 5;    // 0..7: point-slot within block step
    float w[10];
#pragma unroll
    for (int k = 0; k < 10; ++k) w[k] = Wp[c * 10 + k];
    const float bc = bp[c];

    const unsigned s0 = starts[blockIdx.x];
    const unsigned s1 = starts[blockIdx.x + 1];
    __syncthreads();

    // phase 1: sequential stream, max into LDS table
    for (unsigned p = s0 + sub; p < s1; p += 8) {
        const float4* rec = ps4 + (size_t)p * 3;
        float4 v0 = rec[0], v1 = rec[1], v2 = rec[2];
        unsigned meta = __float_as_uint(v2.z);
        unsigned pl = (meta >> 21) & (PPB - 1);
        float a = bc;
        a += v0.x * w[0]; a += v0.y * w[1]; a += v0.z * w[2]; a += v0.w * w[3];
        a += v1.x * w[4]; a += v1.y * w[5]; a += v1.z * w[6]; a += v1.w * w[7];
        a += v2.x * w[8]; a += v2.y * w[9];
        a = fmaxf(a, 0.f);
        atomicMax(&tab[(pl << 5) + c], __float_as_uint(a));
    }
    __syncthreads();

    // phase 2: re-stream (cache-hot), bit-identical recompute, coalesced dword store
    for (unsigned p = s0 + sub; p < s1; p += 8) {
        const float4* rec = ps4 + (size_t)p * 3;
        float4 v0 = rec[0], v1 = rec[1], v2 = rec[2];
        unsigned meta = __float_as_uint(v2.z);
        unsigned idx = meta & 0x1FFFFFu;
        unsigned pl = (meta >> 21) & (PPB - 1);
        float a = bc;
        a += v0.x * w[0]; a += v0.y * w[1]; a += v0.z * w[2]; a += v0.w * w[3];
        a += v1.x * w[4]; a += v1.y * w[5]; a += v1.z * w[6]; a += v1.w * w[7];
        a += v2.x * w[8]; a += v2.y * w[9];
        a = fmaxf(a, 0.f);
        float mx = __uint_as_float(tab[(pl << 5) + c]);
        out[(size_t)idx * 32 + c] = (a + mx) * 0.5f;
    }
}

// ---------------- fallback (small ws): index sort + channel-per-lane gather ----------------
__global__ __launch_bounds__(256) void kC_idx(const int* __restrict__ unq,
                                              const unsigned* __restrict__ off,
                                              unsigned* __restrict__ sorted)
{
    __shared__ unsigned cur[NBKT];
    for (int i = threadIdx.x; i < NBKT; i += 256)
        cur[i] = off[(size_t)blockIdx.x * NBKT + i];
    __syncthreads();
    const int lo = blockIdx.x * CHUNK;
    const int hi = min(lo + CHUNK, NPTS);
    for (int t = lo + threadIdx.x; t < hi; t += 256) {
        int pil = unq[t];
        unsigned slot = atomicAdd(&cur[pil >> SHIFT], 1u);
        sorted[slot] = ((unsigned)(pil & (PPB - 1)) << 21) | (unsigned)t;
    }
}

__global__ __launch_bounds__(256) void kD_idx(const float* __restrict__ in,
                                              const unsigned* __restrict__ starts,
                                              const unsigned* __restrict__ sorted,
                                              const float* __restrict__ Wp,
                                              const float* __restrict__ bp,
                                              float* __restrict__ out)
{
    __shared__ unsigned tab[PPB * 32];
    for (int i = threadIdx.x; i < PPB * 32; i += 256) tab[i] = 0u;

    const int c   = threadIdx.x & 31;
    const int sub = threadIdx.x >> 5;
    float w[10];
#pragma unroll
    for (int k = 0; k < 10; ++k) w[k] = Wp[c * 10 + k];
    const float bc = bp[c];

    const unsigned s0 = starts[blockIdx.x];
    const unsigned s1 = starts[blockIdx.x + 1];
    __syncthreads();

    for (unsigned p = s0 + sub; p < s1; p += 8) {
        unsigned u = sorted[p];
        unsigned idx = u & 0x1FFFFFu, pl = (u >> 21) & (PPB - 1);
        const float* px = in + (size_t)idx * 10;
        float4 v0 = *reinterpret_cast<const float4*>(px);
        float4 v1 = *reinterpret_cast<const float4*>(px + 4);
        float2 v2 = *reinterpret_cast<const float2*>(px + 8);
        float a = bc;
        a += v0.x * w[0]; a += v0.y * w[1]; a += v0.z * w[2]; a += v0.w * w[3];
        a += v1.x * w[4]; a += v1.y * w[5]; a += v1.z * w[6]; a += v1.w * w[7];
        a += v2.x * w[8]; a += v2.y * w[9];
        a = fmaxf(a, 0.f);
        atomicMax(&tab[(pl << 5) + c], __float_as_uint(a));
    }
    __syncthreads();

    for (unsigned p = s0 + sub; p < s1; p += 8) {
        unsigned u = sorted[p];
        unsigned idx = u & 0x1FFFFFu, pl = (u >> 21) & (PPB - 1);
        const float* px = in + (size_t)idx * 10;
        float4 v0 = *reinterpret_cast<const float4*>(px);
        float4 v1 = *reinterpret_cast<const float4*>(px + 4);
        float2 v2 = *reinterpret_cast<const float2*>(px + 8);
        float a = bc;
        a += v0.x * w[0]; a += v0.y * w[1]; a += v0.z * w[2]; a += v0.w * w[3];
        a += v1.x * w[4]; a += v1.y * w[5]; a += v1.z * w[6]; a += v1.w * w[7];
        a += v2.x * w[8]; a += v2.y * w[9];
        a = fmaxf(a, 0.f);
        float mx = __uint_as_float(tab[(pl << 5) + c]);
        out[(size_t)idx * 32 + c] = (a + mx) * 0.5f;
    }
}

extern "C" void kernel_launch(void* const* d_in, const int* in_sizes, int n_in,
                              void* d_out, int out_size, void* d_ws, size_t ws_size,
                              hipStream_t stream)
{
    const float* in    = (const float*)d_in[0];
    const float* W     = (const float*)d_in[1];
    const float* b     = (const float*)d_in[2];
    const float* gamma = (const float*)d_in[3];
    const float* beta  = (const float*)d_in[4];
    const int*   unq   = (const int*)d_in[5];

    float* ws      = (float*)d_ws;
    float* accum   = ws + ACC_OFF;
    float* Wp      = ws + WP_OFF;
    float* bp      = ws + BP_OFF;
    float* partial = ws + PART_OFF;
    unsigned* hist   = (unsigned*)(ws + HIST_OFF);   // becomes offsets after kB3
    unsigned* tots   = (unsigned*)(ws + TOTS_OFF);
    unsigned* starts = (unsigned*)(ws + STARTS_OFF);

    // histogram + role-0 moments fused; role-1 moments in parallel pass
    kA_hist_mom<<<NBAC, 256, 0, stream>>>(in, unq, hist, partial);
    k1_mom1<<<NB, 256, 0, stream>>>(in, partial);
    // offsets
    kB1_colsum<<<NBKT, 64, 0, stream>>>(hist, tots);
    kB2_scan<<<1, 1024, 0, stream>>>(tots, starts);
    kB3_expand<<<NBKT, 64, 0, stream>>>(hist, starts);
    // BN fold
    k1_final<<<65, 64, 0, stream>>>(partial, accum);
    k2_finalize<<<1, 64, 0, stream>>>(accum, W, b, gamma, beta, Wp, bp);

    if (ws_size >= REQ_BYTES) {
        float4* ps4 = (float4*)(ws + PS_OFF);
        kC2_scatter<<<NBAC, 256, 0, stream>>>(in, unq, hist, ps4);
        kD3_reduce<<<NBKT, 256, 0, stream>>>(ps4, starts, Wp, bp, (float*)d_out);
    } else {
        unsigned* sorted = (unsigned*)(ws + PS_OFF);
        kC_idx<<<NBAC, 256, 0, stream>>>(unq, hist, sorted);
        kD_idx<<<NBKT, 256, 0, stream>>>(in, starts, sorted, Wp, bp, (float*)d_out);
    }
}

// Round 7
// 294.278 us; speedup vs baseline: 12.8103x; 1.2556x over previous
//
#include <hip/hip_runtime.h>

#define NPTS    2000000
#define PIL     100000
#define BN_EPS_F 1e-3f

// counting-sort params
#define SHIFT   6
#define PPB     64                  // pillars per bucket
#define NBKT    1563                // ceil(PIL / PPB)
#define NBAC    512                 // blocks for hist/scatter passes
#define CHUNK   3907                // ceil(NPTS / NBAC)

// d_ws float-index offsets
#define ACC_OFF    0                // 65 f
#define WP_OFF     128              // 320 f
#define BP_OFF     512              // 32 f
#define PART_OFF   1024             // 65*NBAC f (end 34,304)
#define HIST_OFF   34816            // NBAC*NBKT u32 (end 835,072); kB3 rewrites in place
#define TOTS_OFF   835584           // NBKT u32
#define STARTS_OFF 837632           // NBKT+1 u32
#define PS_OFF     839680           // NPTS*12 f  (~99.4 MB total; proven available R5/R6)

__device__ __forceinline__ constexpr int tri_idx(int j, int k) {
    return j * 10 - j * (j - 1) / 2 + (k - j);
}

// ---------------- kA: bucket histogram only (reads unq, 8 MB) ----------------
__global__ __launch_bounds__(256) void kA_hist(const int* __restrict__ unq,
                                               unsigned* __restrict__ hist)
{
    __shared__ unsigned h[NBKT];
    for (int i = threadIdx.x; i < NBKT; i += 256) h[i] = 0u;
    __syncthreads();
    const int lo = blockIdx.x * CHUNK;
    const int hi = min(lo + CHUNK, NPTS);
    for (int t = lo + threadIdx.x; t < hi; t += 256)
        atomicAdd(&h[unq[t] >> SHIFT], 1u);
    __syncthreads();
    for (int i = threadIdx.x; i < NBKT; i += 256)
        hist[(size_t)blockIdx.x * NBKT + i] = h[i];
}

// ---------------- kB1: per-bucket totals ----------------
__global__ __launch_bounds__(64) void kB1_colsum(const unsigned* __restrict__ hist,
                                                 unsigned* __restrict__ tots)
{
    const int c = blockIdx.x, lane = threadIdx.x;
    unsigned s = 0;
#pragma unroll
    for (int i = 0; i < NBAC / 64; ++i) s += hist[(size_t)(i * 64 + lane) * NBKT + c];
#pragma unroll
    for (int sh = 1; sh < 64; sh <<= 1) s += __shfl_xor(s, sh, 64);
    if (lane == 0) tots[c] = s;
}

// ---------------- kB2: scan totals (1563) -> bucket starts; 2 elems/thread ----------------
__global__ __launch_bounds__(1024) void kB2_scan(const unsigned* __restrict__ tots,
                                                 unsigned* __restrict__ starts)
{
    __shared__ unsigned ps[1024];
    const int t = threadIdx.x;
    unsigned v0 = (2*t     < NBKT) ? tots[2*t]     : 0u;
    unsigned v1 = (2*t + 1 < NBKT) ? tots[2*t + 1] : 0u;
    unsigned pair = v0 + v1;
    ps[t] = pair;
    __syncthreads();
    for (int d = 1; d < 1024; d <<= 1) {
        unsigned v = (t >= d) ? ps[t - d] : 0u;
        __syncthreads();
        ps[t] += v;
        __syncthreads();
    }
    unsigned excl = ps[t] - pair;
    if (2*t     < NBKT) starts[2*t]     = excl;
    if (2*t + 1 < NBKT) starts[2*t + 1] = excl + v0;
    if (t == 1023) starts[NBKT] = ps[1023];
}

// ---------------- kB3: expand per-(block,bucket) offsets IN PLACE over hist ----------------
__global__ __launch_bounds__(64) void kB3_expand(unsigned* __restrict__ hist,
                                                 const unsigned* __restrict__ starts)
{
    const int c = blockIdx.x, lane = threadIdx.x;
    unsigned hv[NBAC / 64];
    unsigned psum = 0;
#pragma unroll
    for (int i = 0; i < NBAC / 64; ++i) {
        hv[i] = hist[(size_t)(lane * (NBAC / 64) + i) * NBKT + c];
        psum += hv[i];
    }
    unsigned incl = psum;
#pragma unroll
    for (int s = 1; s < 64; s <<= 1) {
        unsigned v = __shfl_up(incl, s, 64);
        if (lane >= s) incl += v;
    }
    unsigned run = starts[c] + (incl - psum);
#pragma unroll
    for (int i = 0; i < NBAC / 64; ++i) {
        hist[(size_t)(lane * (NBAC / 64) + i) * NBKT + c] = run;
        run += hv[i];
    }
}

// ---------------- kC2: scatter 48B records into bucket order + ALL 65 moments ----------------
__global__ __launch_bounds__(256) void kC2_scatter_mom(const float* __restrict__ in,
                                                       const int* __restrict__ unq,
                                                       const unsigned* __restrict__ off,
                                                       float4* __restrict__ ps4,
                                                       float* __restrict__ partial)
{
    __shared__ unsigned cur[NBKT];
    __shared__ float lds2[4][66];
    for (int i = threadIdx.x; i < NBKT; i += 256)
        cur[i] = off[(size_t)blockIdx.x * NBKT + i];
    __syncthreads();

    float acc[65];
#pragma unroll
    for (int i = 0; i < 65; ++i) acc[i] = 0.f;

    const int lo = blockIdx.x * CHUNK;
    const int hi = min(lo + CHUNK, NPTS);
    for (int t = lo + threadIdx.x; t < hi; t += 256) {
        int pil = unq[t];
        unsigned slot = atomicAdd(&cur[pil >> SHIFT], 1u);
        const float* px = in + (size_t)t * 10;
        float4 r0 = *reinterpret_cast<const float4*>(px);
        float4 r1 = *reinterpret_cast<const float4*>(px + 4);
        float2 r2 = *reinterpret_cast<const float2*>(px + 8);
        unsigned meta = ((unsigned)(pil & (PPB - 1)) << 21) | (unsigned)t;
        float4* d = ps4 + (size_t)slot * 3;
        d[0] = r0;
        d[1] = r1;
        d[2] = make_float4(r2.x, r2.y, __uint_as_float(meta), 0.f);

        float xf[10] = { r0.x, r0.y, r0.z, r0.w, r1.x, r1.y, r1.z, r1.w, r2.x, r2.y };
#pragma unroll
        for (int j = 0; j < 10; ++j) acc[j] += xf[j];
        int o = 10;
#pragma unroll
        for (int j = 0; j < 10; ++j)
#pragma unroll
            for (int k = j; k < 10; ++k) acc[o++] += xf[j] * xf[k];
    }

#pragma unroll
    for (int i = 0; i < 65; ++i) {
        float v = acc[i];
#pragma unroll
        for (int s = 1; s < 64; s <<= 1) v += __shfl_xor(v, s, 64);
        acc[i] = v;
    }
    const int wid = threadIdx.x >> 6, lane = threadIdx.x & 63;
    if (lane == 0) {
#pragma unroll
        for (int i = 0; i < 65; ++i) lds2[wid][i] = acc[i];
    }
    __syncthreads();
    if (threadIdx.x < 65) {
        float s = lds2[0][threadIdx.x] + lds2[1][threadIdx.x]
                + lds2[2][threadIdx.x] + lds2[3][threadIdx.x];
        partial[(size_t)threadIdx.x * NBAC + blockIdx.x] = s;
    }
}

// ---------------- k1f: reduce partials -> accum[65] ----------------
__global__ void k1_final(const float* __restrict__ partial, float* __restrict__ accum)
{
    const int e = blockIdx.x, lane = threadIdx.x;
    float s = 0.f;
#pragma unroll
    for (int i = 0; i < NBAC / 64; ++i) s += partial[(size_t)e * NBAC + i * 64 + lane];
#pragma unroll
    for (int sh = 1; sh < 64; sh <<= 1) s += __shfl_xor(s, sh, 64);
    if (lane == 0) accum[e] = s;
}

// ---------------- k2: finalize BN -> folded W', b' ----------------
__global__ void k2_finalize(const float* __restrict__ accum, const float* __restrict__ W,
                            const float* __restrict__ b, const float* __restrict__ gamma,
                            const float* __restrict__ beta, float* __restrict__ Wp,
                            float* __restrict__ bp)
{
    int c = threadIdx.x;
    if (c >= 32) return;
    const float invN = 1.0f / (float)NPTS;
    float m[10], w[10];
#pragma unroll
    for (int k = 0; k < 10; ++k) m[k] = accum[k] * invN;
#pragma unroll
    for (int k = 0; k < 10; ++k) w[k] = W[c*10 + k];
    float mean = b[c];
#pragma unroll
    for (int k = 0; k < 10; ++k) mean += w[k] * m[k];
    float var = 0.f;
#pragma unroll
    for (int j = 0; j < 10; ++j) {
#pragma unroll
        for (int k = j; k < 10; ++k) {
            float Cjk = accum[10 + tri_idx(j, k)] * invN - m[j] * m[k];
            var += w[j] * w[k] * Cjk * ((j == k) ? 1.f : 2.f);
        }
    }
    float scale = gamma[c] * rsqrtf(var + BN_EPS_F);
#pragma unroll
    for (int k = 0; k < 10; ++k) Wp[c*10 + k] = w[k] * scale;
    bp[c] = (b[c] - mean) * scale + beta[c];
}

// ---------------- kD4: channel-per-lane, 4x-unrolled prefetch ----------------
__device__ __forceinline__ float kd_affine(const float4& v0, const float4& v1,
                                           const float4& v2, const float* w, float bc)
{
    float a = bc;
    a += v0.x * w[0]; a += v0.y * w[1]; a += v0.z * w[2]; a += v0.w * w[3];
    a += v1.x * w[4]; a += v1.y * w[5]; a += v1.z * w[6]; a += v1.w * w[7];
    a += v2.x * w[8]; a += v2.y * w[9];
    return fmaxf(a, 0.f);
}

__global__ __launch_bounds__(256) void kD4_reduce(const float4* __restrict__ ps4,
                                                  const unsigned* __restrict__ starts,
                                                  const float* __restrict__ Wp,
                                                  const float* __restrict__ bp,
                                                  float* __restrict__ out)
{
    __shared__ unsigned tab[PPB * 32];   // 8 KB; tab[pl*32+c] -> bank c, 2-way free
    for (int i = threadIdx.x; i < PPB * 32; i += 256) tab[i] = 0u;

    const int c   = threadIdx.x & 31;
    const int sub = threadIdx.x >> 5;    // 0..7
    float w[10];
#pragma unroll
    for (int k = 0; k < 10; ++k) w[k] = Wp[c * 10 + k];
    const float bc = bp[c];

    const unsigned s0 = starts[blockIdx.x];
    const unsigned s1 = starts[blockIdx.x + 1];
    __syncthreads();

    // ---- phase 1: max into LDS table; 4 points' loads in flight ----
    unsigned p = s0 + sub;
    for (; p + 24 < s1; p += 32) {
        float4 r[4][3];
#pragma unroll
        for (int u = 0; u < 4; ++u) {
            const float4* rec = ps4 + (size_t)(p + 8u * u) * 3;
            r[u][0] = rec[0]; r[u][1] = rec[1]; r[u][2] = rec[2];
        }
#pragma unroll
        for (int u = 0; u < 4; ++u) {
            unsigned meta = __float_as_uint(r[u][2].z);
            unsigned pl = (meta >> 21) & (PPB - 1);
            float a = kd_affine(r[u][0], r[u][1], r[u][2], w, bc);
            atomicMax(&tab[(pl << 5) + c], __float_as_uint(a));
        }
    }
    for (; p < s1; p += 8) {
        const float4* rec = ps4 + (size_t)p * 3;
        float4 v0 = rec[0], v1 = rec[1], v2 = rec[2];
        unsigned meta = __float_as_uint(v2.z);
        unsigned pl = (meta >> 21) & (PPB - 1);
        float a = kd_affine(v0, v1, v2, w, bc);
        atomicMax(&tab[(pl << 5) + c], __float_as_uint(a));
    }
    __syncthreads();

    // ---- phase 2: recompute (cache-hot), combine, nontemporal coalesced store ----
    p = s0 + sub;
    for (; p + 24 < s1; p += 32) {
        float4 r[4][3];
#pragma unroll
        for (int u = 0; u < 4; ++u) {
            const float4* rec = ps4 + (size_t)(p + 8u * u) * 3;
            r[u][0] = rec[0]; r[u][1] = rec[1]; r[u][2] = rec[2];
        }
#pragma unroll
        for (int u = 0; u < 4; ++u) {
            unsigned meta = __float_as_uint(r[u][2].z);
            unsigned idx = meta & 0x1FFFFFu;
            unsigned pl = (meta >> 21) & (PPB - 1);
            float a = kd_affine(r[u][0], r[u][1], r[u][2], w, bc);
            float mx = __uint_as_float(tab[(pl << 5) + c]);
            __builtin_nontemporal_store((a + mx) * 0.5f, &out[(size_t)idx * 32 + c]);
        }
    }
    for (; p < s1; p += 8) {
        const float4* rec = ps4 + (size_t)p * 3;
        float4 v0 = rec[0], v1 = rec[1], v2 = rec[2];
        unsigned meta = __float_as_uint(v2.z);
        unsigned idx = meta & 0x1FFFFFu;
        unsigned pl = (meta >> 21) & (PPB - 1);
        float a = kd_affine(v0, v1, v2, w, bc);
        float mx = __uint_as_float(tab[(pl << 5) + c]);
        __builtin_nontemporal_store((a + mx) * 0.5f, &out[(size_t)idx * 32 + c]);
    }
}

extern "C" void kernel_launch(void* const* d_in, const int* in_sizes, int n_in,
                              void* d_out, int out_size, void* d_ws, size_t ws_size,
                              hipStream_t stream)
{
    const float* in    = (const float*)d_in[0];
    const float* W     = (const float*)d_in[1];
    const float* b     = (const float*)d_in[2];
    const float* gamma = (const float*)d_in[3];
    const float* beta  = (const float*)d_in[4];
    const int*   unq   = (const int*)d_in[5];

    float* ws      = (float*)d_ws;
    float* accum   = ws + ACC_OFF;
    float* Wp      = ws + WP_OFF;
    float* bp      = ws + BP_OFF;
    float* partial = ws + PART_OFF;
    unsigned* hist   = (unsigned*)(ws + HIST_OFF);   // becomes offsets after kB3
    unsigned* tots   = (unsigned*)(ws + TOTS_OFF);
    unsigned* starts = (unsigned*)(ws + STARTS_OFF);
    float4*   ps4    = (float4*)(ws + PS_OFF);

    // bucket histogram (unq only) -> offsets
    kA_hist<<<NBAC, 256, 0, stream>>>(unq, hist);
    kB1_colsum<<<NBKT, 64, 0, stream>>>(hist, tots);
    kB2_scan<<<1, 1024, 0, stream>>>(tots, starts);
    kB3_expand<<<NBKT, 64, 0, stream>>>(hist, starts);
    // sort full records + accumulate all 65 input moments in the same pass
    kC2_scatter_mom<<<NBAC, 256, 0, stream>>>(in, unq, hist, ps4, partial);
    // BN fold
    k1_final<<<65, 64, 0, stream>>>(partial, accum);
    k2_finalize<<<1, 64, 0, stream>>>(accum, W, b, gamma, beta, Wp, bp);
    // per-bucket LDS segment-max + fused output
    kD4_reduce<<<NBKT, 256, 0, stream>>>(ps4, starts, Wp, bp, (float*)d_out);
}

// Round 8
// 284.361 us; speedup vs baseline: 13.2571x; 1.0349x over previous
//
#include <hip/hip_runtime.h>

#define NPTS    2000000
#define PIL     100000
#define BN_EPS_F 1e-3f

// counting-sort params
#define SHIFT   5
#define PPB     32                  // pillars per bucket
#define NBKT    3125                // ceil(PIL / PPB)
#define NBAC    256                 // blocks for hist/scatter passes
#define CHUNK   7813                // ceil(NPTS / NBAC)

// d_ws float-index offsets (PS_OFF kept at the R5/R6/R7-proven value)
#define ACC_OFF    0                // 65 f
#define WP_OFF     128              // 320 f
#define BP_OFF     512              // 32 f
#define PART_OFF   1024             // 65*NBAC f (end 17,664)
#define TOTS_OFF   17920            // NBKT u32
#define STARTS_OFF 21248            // NBKT+1 u32
#define HIST_OFF   24576            // NBAC*NBKT u32 (end 824,576); kB3 rewrites in place
#define PS_OFF     839680           // NPTS*12 f (~99.4 MB total; proven available)

__device__ __forceinline__ constexpr int tri_idx(int j, int k) {
    return j * 10 - j * (j - 1) / 2 + (k - j);
}

// ---------------- kA: bucket histogram only (reads unq, 8 MB) ----------------
__global__ __launch_bounds__(256) void kA_hist(const int* __restrict__ unq,
                                               unsigned* __restrict__ hist)
{
    __shared__ unsigned h[NBKT];
    for (int i = threadIdx.x; i < NBKT; i += 256) h[i] = 0u;
    __syncthreads();
    const int lo = blockIdx.x * CHUNK;
    const int hi = min(lo + CHUNK, NPTS);
    for (int t = lo + threadIdx.x; t < hi; t += 256)
        atomicAdd(&h[unq[t] >> SHIFT], 1u);
    __syncthreads();
    for (int i = threadIdx.x; i < NBKT; i += 256)
        hist[(size_t)blockIdx.x * NBKT + i] = h[i];
}

// ---------------- kB1: per-bucket totals ----------------
__global__ __launch_bounds__(64) void kB1_colsum(const unsigned* __restrict__ hist,
                                                 unsigned* __restrict__ tots)
{
    const int c = blockIdx.x, lane = threadIdx.x;
    unsigned s = 0;
#pragma unroll
    for (int i = 0; i < NBAC / 64; ++i) s += hist[(size_t)(i * 64 + lane) * NBKT + c];
#pragma unroll
    for (int sh = 1; sh < 64; sh <<= 1) s += __shfl_xor(s, sh, 64);
    if (lane == 0) tots[c] = s;
}

// ---------------- kB2: scan totals (3125) -> bucket starts; 4 elems/thread ----------------
__global__ __launch_bounds__(1024) void kB2_scan(const unsigned* __restrict__ tots,
                                                 unsigned* __restrict__ starts)
{
    __shared__ unsigned ps[1024];
    const int t = threadIdx.x;
    unsigned v[4], sum = 0;
#pragma unroll
    for (int i = 0; i < 4; ++i) {
        int idx = t * 4 + i;
        v[i] = (idx < NBKT) ? tots[idx] : 0u;
        sum += v[i];
    }
    ps[t] = sum;
    __syncthreads();
    for (int d = 1; d < 1024; d <<= 1) {
        unsigned x = (t >= d) ? ps[t - d] : 0u;
        __syncthreads();
        ps[t] += x;
        __syncthreads();
    }
    unsigned excl = ps[t] - sum;
#pragma unroll
    for (int i = 0; i < 4; ++i) {
        int idx = t * 4 + i;
        if (idx < NBKT) starts[idx] = excl;
        excl += v[i];
    }
    if (t == 1023) starts[NBKT] = ps[1023];
}

// ---------------- kB3: expand per-(block,bucket) offsets IN PLACE over hist ----------------
__global__ __launch_bounds__(64) void kB3_expand(unsigned* __restrict__ hist,
                                                 const unsigned* __restrict__ starts)
{
    const int c = blockIdx.x, lane = threadIdx.x;
    unsigned hv[NBAC / 64];
    unsigned psum = 0;
#pragma unroll
    for (int i = 0; i < NBAC / 64; ++i) {
        hv[i] = hist[(size_t)(lane * (NBAC / 64) + i) * NBKT + c];
        psum += hv[i];
    }
    unsigned incl = psum;
#pragma unroll
    for (int s = 1; s < 64; s <<= 1) {
        unsigned v = __shfl_up(incl, s, 64);
        if (lane >= s) incl += v;
    }
    unsigned run = starts[c] + (incl - psum);
#pragma unroll
    for (int i = 0; i < NBAC / 64; ++i) {
        hist[(size_t)(lane * (NBAC / 64) + i) * NBKT + c] = run;
        run += hv[i];
    }
}

// ---------------- kC2: scatter 48B records into bucket order + ALL 65 moments ----------------
__global__ __launch_bounds__(256) void kC2_scatter_mom(const float* __restrict__ in,
                                                       const int* __restrict__ unq,
                                                       const unsigned* __restrict__ off,
                                                       float4* __restrict__ ps4,
                                                       float* __restrict__ partial)
{
    __shared__ unsigned cur[NBKT];
    __shared__ float lds2[4][66];
    for (int i = threadIdx.x; i < NBKT; i += 256)
        cur[i] = off[(size_t)blockIdx.x * NBKT + i];
    __syncthreads();

    float acc[65];
#pragma unroll
    for (int i = 0; i < 65; ++i) acc[i] = 0.f;

    const int lo = blockIdx.x * CHUNK;
    const int hi = min(lo + CHUNK, NPTS);
    for (int t = lo + threadIdx.x; t < hi; t += 256) {
        int pil = unq[t];
        unsigned slot = atomicAdd(&cur[pil >> SHIFT], 1u);
        const float* px = in + (size_t)t * 10;
        float4 r0 = *reinterpret_cast<const float4*>(px);
        float4 r1 = *reinterpret_cast<const float4*>(px + 4);
        float2 r2 = *reinterpret_cast<const float2*>(px + 8);
        unsigned meta = ((unsigned)(pil & (PPB - 1)) << 21) | (unsigned)t;
        float4* d = ps4 + (size_t)slot * 3;
        d[0] = r0;
        d[1] = r1;
        d[2] = make_float4(r2.x, r2.y, __uint_as_float(meta), 0.f);

        float xf[10] = { r0.x, r0.y, r0.z, r0.w, r1.x, r1.y, r1.z, r1.w, r2.x, r2.y };
#pragma unroll
        for (int j = 0; j < 10; ++j) acc[j] += xf[j];
        int o = 10;
#pragma unroll
        for (int j = 0; j < 10; ++j)
#pragma unroll
            for (int k = j; k < 10; ++k) acc[o++] += xf[j] * xf[k];
    }

#pragma unroll
    for (int i = 0; i < 65; ++i) {
        float v = acc[i];
#pragma unroll
        for (int s = 1; s < 64; s <<= 1) v += __shfl_xor(v, s, 64);
        acc[i] = v;
    }
    const int wid = threadIdx.x >> 6, lane = threadIdx.x & 63;
    if (lane == 0) {
#pragma unroll
        for (int i = 0; i < 65; ++i) lds2[wid][i] = acc[i];
    }
    __syncthreads();
    if (threadIdx.x < 65) {
        float s = lds2[0][threadIdx.x] + lds2[1][threadIdx.x]
                + lds2[2][threadIdx.x] + lds2[3][threadIdx.x];
        partial[(size_t)threadIdx.x * NBAC + blockIdx.x] = s;
    }
}

// ---------------- k1f: reduce partials -> accum[65] ----------------
__global__ void k1_final(const float* __restrict__ partial, float* __restrict__ accum)
{
    const int e = blockIdx.x, lane = threadIdx.x;
    float s = 0.f;
#pragma unroll
    for (int i = 0; i < NBAC / 64; ++i) s += partial[(size_t)e * NBAC + i * 64 + lane];
#pragma unroll
    for (int sh = 1; sh < 64; sh <<= 1) s += __shfl_xor(s, sh, 64);
    if (lane == 0) accum[e] = s;
}

// ---------------- k2: finalize BN -> folded W', b' ----------------
__global__ void k2_finalize(const float* __restrict__ accum, const float* __restrict__ W,
                            const float* __restrict__ b, const float* __restrict__ gamma,
                            const float* __restrict__ beta, float* __restrict__ Wp,
                            float* __restrict__ bp)
{
    int c = threadIdx.x;
    if (c >= 32) return;
    const float invN = 1.0f / (float)NPTS;
    float m[10], w[10];
#pragma unroll
    for (int k = 0; k < 10; ++k) m[k] = accum[k] * invN;
#pragma unroll
    for (int k = 0; k < 10; ++k) w[k] = W[c*10 + k];
    float mean = b[c];
#pragma unroll
    for (int k = 0; k < 10; ++k) mean += w[k] * m[k];
    float var = 0.f;
#pragma unroll
    for (int j = 0; j < 10; ++j) {
#pragma unroll
        for (int k = j; k < 10; ++k) {
            float Cjk = accum[10 + tri_idx(j, k)] * invN - m[j] * m[k];
            var += w[j] * w[k] * Cjk * ((j == k) ? 1.f : 2.f);
        }
    }
    float scale = gamma[c] * rsqrtf(var + BN_EPS_F);
#pragma unroll
    for (int k = 0; k < 10; ++k) Wp[c*10 + k] = w[k] * scale;
    bp[c] = (b[c] - mean) * scale + beta[c];
}

// ---------------- kD5: channel-per-lane, high-occupancy small buckets ----------------
__device__ __forceinline__ float kd_affine(const float4& v0, const float4& v1,
                                           const float4& v2, const float* w, float bc)
{
    float a = bc;
    a += v0.x * w[0]; a += v0.y * w[1]; a += v0.z * w[2]; a += v0.w * w[3];
    a += v1.x * w[4]; a += v1.y * w[5]; a += v1.z * w[6]; a += v1.w * w[7];
    a += v2.x * w[8]; a += v2.y * w[9];
    return fmaxf(a, 0.f);
}

__global__ __launch_bounds__(256) void kD5_reduce(const float4* __restrict__ ps4,
                                                  const unsigned* __restrict__ starts,
                                                  const float* __restrict__ Wp,
                                                  const float* __restrict__ bp,
                                                  float* __restrict__ out)
{
    __shared__ unsigned tab[PPB * 32];   // 4 KB; tab[pl*32+c] -> bank c, 2-way free
    for (int i = threadIdx.x; i < PPB * 32; i += 256) tab[i] = 0u;

    const int c   = threadIdx.x & 31;
    const int sub = threadIdx.x >> 5;    // 0..7
    float w[10];
#pragma unroll
    for (int k = 0; k < 10; ++k) w[k] = Wp[c * 10 + k];
    const float bc = bp[c];

    const unsigned s0 = starts[blockIdx.x];
    const unsigned s1 = starts[blockIdx.x + 1];
    __syncthreads();

    // ---- phase 1: max into LDS table; 4 points' loads batched ----
    unsigned p = s0 + sub;
    for (; p + 24 < s1; p += 32) {
        float4 r[4][3];
#pragma unroll
        for (int u = 0; u < 4; ++u) {
            const float4* rec = ps4 + (size_t)(p + 8u * u) * 3;
            r[u][0] = rec[0]; r[u][1] = rec[1]; r[u][2] = rec[2];
        }
#pragma unroll
        for (int u = 0; u < 4; ++u) {
            unsigned meta = __float_as_uint(r[u][2].z);
            unsigned pl = (meta >> 21) & (PPB - 1);
            float a = kd_affine(r[u][0], r[u][1], r[u][2], w, bc);
            atomicMax(&tab[(pl << 5) + c], __float_as_uint(a));
        }
    }
    for (; p < s1; p += 8) {
        const float4* rec = ps4 + (size_t)p * 3;
        float4 v0 = rec[0], v1 = rec[1], v2 = rec[2];
        unsigned meta = __float_as_uint(v2.z);
        unsigned pl = (meta >> 21) & (PPB - 1);
        float a = kd_affine(v0, v1, v2, w, bc);
        atomicMax(&tab[(pl << 5) + c], __float_as_uint(a));
    }
    __syncthreads();

    // ---- phase 2: recompute (cache-hot), combine, nontemporal coalesced store ----
    p = s0 + sub;
    for (; p + 24 < s1; p += 32) {
        float4 r[4][3];
#pragma unroll
        for (int u = 0; u < 4; ++u) {
            const float4* rec = ps4 + (size_t)(p + 8u * u) * 3;
            r[u][0] = rec[0]; r[u][1] = rec[1]; r[u][2] = rec[2];
        }
#pragma unroll
        for (int u = 0; u < 4; ++u) {
            unsigned meta = __float_as_uint(r[u][2].z);
            unsigned idx = meta & 0x1FFFFFu;
            unsigned pl = (meta >> 21) & (PPB - 1);
            float a = kd_affine(r[u][0], r[u][1], r[u][2], w, bc);
            float mx = __uint_as_float(tab[(pl << 5) + c]);
            __builtin_nontemporal_store((a + mx) * 0.5f, &out[(size_t)idx * 32 + c]);
        }
    }
    for (; p < s1; p += 8) {
        const float4* rec = ps4 + (size_t)p * 3;
        float4 v0 = rec[0], v1 = rec[1], v2 = rec[2];
        unsigned meta = __float_as_uint(v2.z);
        unsigned idx = meta & 0x1FFFFFu;
        unsigned pl = (meta >> 21) & (PPB - 1);
        float a = kd_affine(v0, v1, v2, w, bc);
        float mx = __uint_as_float(tab[(pl << 5) + c]);
        __builtin_nontemporal_store((a + mx) * 0.5f, &out[(size_t)idx * 32 + c]);
    }
}

extern "C" void kernel_launch(void* const* d_in, const int* in_sizes, int n_in,
                              void* d_out, int out_size, void* d_ws, size_t ws_size,
                              hipStream_t stream)
{
    const float* in    = (const float*)d_in[0];
    const float* W     = (const float*)d_in[1];
    const float* b     = (const float*)d_in[2];
    const float* gamma = (const float*)d_in[3];
    const float* beta  = (const float*)d_in[4];
    const int*   unq   = (const int*)d_in[5];

    float* ws      = (float*)d_ws;
    float* accum   = ws + ACC_OFF;
    float* Wp      = ws + WP_OFF;
    float* bp      = ws + BP_OFF;
    float* partial = ws + PART_OFF;
    unsigned* tots   = (unsigned*)(ws + TOTS_OFF);
    unsigned* starts = (unsigned*)(ws + STARTS_OFF);
    unsigned* hist   = (unsigned*)(ws + HIST_OFF);   // becomes offsets after kB3
    float4*   ps4    = (float4*)(ws + PS_OFF);

    // bucket histogram (unq only) -> offsets
    kA_hist<<<NBAC, 256, 0, stream>>>(unq, hist);
    kB1_colsum<<<NBKT, 64, 0, stream>>>(hist, tots);
    kB2_scan<<<1, 1024, 0, stream>>>(tots, starts);
    kB3_expand<<<NBKT, 64, 0, stream>>>(hist, starts);
    // sort full records + accumulate all 65 input moments in the same pass
    kC2_scatter_mom<<<NBAC, 256, 0, stream>>>(in, unq, hist, ps4, partial);
    // BN fold
    k1_final<<<65, 64, 0, stream>>>(partial, accum);
    k2_finalize<<<1, 64, 0, stream>>>(accum, W, b, gamma, beta, Wp, bp);
    // per-bucket LDS segment-max + fused output
    kD5_reduce<<<NBKT, 256, 0, stream>>>(ps4, starts, Wp, bp, (float*)d_out);
}

// Round 9
// 187.351 us; speedup vs baseline: 20.1216x; 1.5178x over previous
//
#include <hip/hip_runtime.h>

#define NPTS    2000000
#define PIL     100000
#define BN_EPS_F 1e-3f

// counting-sort params
#define SHIFT   5
#define PPB     32                  // pillars per bucket
#define NBKT    3125                // ceil(PIL / PPB)
#define NBAC    256                 // blocks for hist/scatter passes
#define CHUNK   7813                // ceil(NPTS / NBAC)
#define TILE    64                  // records per kD pipeline chunk
#define TDW     (TILE * 12)         // dwords per chunk = 768

// d_ws float-index offsets (PS_OFF kept at the R5..R8-proven value)
#define ACC_OFF    0                // 65 f
#define WP_OFF     128              // 320 f
#define BP_OFF     512              // 32 f
#define PART_OFF   1024             // 65*NBAC f (end 17,664)
#define TOTS_OFF   17920            // NBKT u32
#define STARTS_OFF 21248            // NBKT+1 u32
#define HIST_OFF   24576            // NBAC*NBKT u32 (end 824,576); kB3 rewrites in place
#define PS_OFF     839680           // NPTS*12 f (~99.4 MB total; proven available)

__device__ __forceinline__ constexpr int tri_idx(int j, int k) {
    return j * 10 - j * (j - 1) / 2 + (k - j);
}

// ---------------- kA: bucket histogram only (reads unq, 8 MB) ----------------
__global__ __launch_bounds__(512) void kA_hist(const int* __restrict__ unq,
                                               unsigned* __restrict__ hist)
{
    __shared__ unsigned h[NBKT];
    for (int i = threadIdx.x; i < NBKT; i += 512) h[i] = 0u;
    __syncthreads();
    const int lo = blockIdx.x * CHUNK;
    const int hi = min(lo + CHUNK, NPTS);
    for (int t = lo + threadIdx.x; t < hi; t += 512)
        atomicAdd(&h[unq[t] >> SHIFT], 1u);
    __syncthreads();
    for (int i = threadIdx.x; i < NBKT; i += 512)
        hist[(size_t)blockIdx.x * NBKT + i] = h[i];
}

// ---------------- kB1: per-bucket totals ----------------
__global__ __launch_bounds__(64) void kB1_colsum(const unsigned* __restrict__ hist,
                                                 unsigned* __restrict__ tots)
{
    const int c = blockIdx.x, lane = threadIdx.x;
    unsigned s = 0;
#pragma unroll
    for (int i = 0; i < NBAC / 64; ++i) s += hist[(size_t)(i * 64 + lane) * NBKT + c];
#pragma unroll
    for (int sh = 1; sh < 64; sh <<= 1) s += __shfl_xor(s, sh, 64);
    if (lane == 0) tots[c] = s;
}

// ---------------- kB2: scan totals (3125) -> bucket starts; 4 elems/thread ----------------
__global__ __launch_bounds__(1024) void kB2_scan(const unsigned* __restrict__ tots,
                                                 unsigned* __restrict__ starts)
{
    __shared__ unsigned ps[1024];
    const int t = threadIdx.x;
    unsigned v[4], sum = 0;
#pragma unroll
    for (int i = 0; i < 4; ++i) {
        int idx = t * 4 + i;
        v[i] = (idx < NBKT) ? tots[idx] : 0u;
        sum += v[i];
    }
    ps[t] = sum;
    __syncthreads();
    for (int d = 1; d < 1024; d <<= 1) {
        unsigned x = (t >= d) ? ps[t - d] : 0u;
        __syncthreads();
        ps[t] += x;
        __syncthreads();
    }
    unsigned excl = ps[t] - sum;
#pragma unroll
    for (int i = 0; i < 4; ++i) {
        int idx = t * 4 + i;
        if (idx < NBKT) starts[idx] = excl;
        excl += v[i];
    }
    if (t == 1023) starts[NBKT] = ps[1023];
}

// ---------------- kB3: expand per-(block,bucket) offsets IN PLACE over hist ----------------
__global__ __launch_bounds__(64) void kB3_expand(unsigned* __restrict__ hist,
                                                 const unsigned* __restrict__ starts)
{
    const int c = blockIdx.x, lane = threadIdx.x;
    unsigned hv[NBAC / 64];
    unsigned psum = 0;
#pragma unroll
    for (int i = 0; i < NBAC / 64; ++i) {
        hv[i] = hist[(size_t)(lane * (NBAC / 64) + i) * NBKT + c];
        psum += hv[i];
    }
    unsigned incl = psum;
#pragma unroll
    for (int s = 1; s < 64; s <<= 1) {
        unsigned v = __shfl_up(incl, s, 64);
        if (lane >= s) incl += v;
    }
    unsigned run = starts[c] + (incl - psum);
#pragma unroll
    for (int i = 0; i < NBAC / 64; ++i) {
        hist[(size_t)(lane * (NBAC / 64) + i) * NBKT + c] = run;
        run += hv[i];
    }
}

// ---------------- kC2: scatter 48B records into bucket order + ALL 65 moments ----------------
__global__ __launch_bounds__(512) void kC2_scatter_mom(const float* __restrict__ in,
                                                       const int* __restrict__ unq,
                                                       const unsigned* __restrict__ off,
                                                       float4* __restrict__ ps4,
                                                       float* __restrict__ partial)
{
    __shared__ unsigned cur[NBKT];
    __shared__ float lds2[8][66];
    for (int i = threadIdx.x; i < NBKT; i += 512)
        cur[i] = off[(size_t)blockIdx.x * NBKT + i];
    __syncthreads();

    float acc[65];
#pragma unroll
    for (int i = 0; i < 65; ++i) acc[i] = 0.f;

    const int lo = blockIdx.x * CHUNK;
    const int hi = min(lo + CHUNK, NPTS);
    for (int t = lo + threadIdx.x; t < hi; t += 512) {
        int pil = unq[t];
        unsigned slot = atomicAdd(&cur[pil >> SHIFT], 1u);
        const float* px = in + (size_t)t * 10;
        float4 r0 = *reinterpret_cast<const float4*>(px);
        float4 r1 = *reinterpret_cast<const float4*>(px + 4);
        float2 r2 = *reinterpret_cast<const float2*>(px + 8);
        unsigned meta = ((unsigned)(pil & (PPB - 1)) << 21) | (unsigned)t;
        float4* d = ps4 + (size_t)slot * 3;
        d[0] = r0;
        d[1] = r1;
        d[2] = make_float4(r2.x, r2.y, __uint_as_float(meta), 0.f);

        float xf[10] = { r0.x, r0.y, r0.z, r0.w, r1.x, r1.y, r1.z, r1.w, r2.x, r2.y };
#pragma unroll
        for (int j = 0; j < 10; ++j) acc[j] += xf[j];
        int o = 10;
#pragma unroll
        for (int j = 0; j < 10; ++j)
#pragma unroll
            for (int k = j; k < 10; ++k) acc[o++] += xf[j] * xf[k];
    }

#pragma unroll
    for (int i = 0; i < 65; ++i) {
        float v = acc[i];
#pragma unroll
        for (int s = 1; s < 64; s <<= 1) v += __shfl_xor(v, s, 64);
        acc[i] = v;
    }
    const int wid = threadIdx.x >> 6, lane = threadIdx.x & 63;
    if (lane == 0) {
#pragma unroll
        for (int i = 0; i < 65; ++i) lds2[wid][i] = acc[i];
    }
    __syncthreads();
    if (threadIdx.x < 65) {
        float s = 0.f;
#pragma unroll
        for (int wv = 0; wv < 8; ++wv) s += lds2[wv][threadIdx.x];
        partial[(size_t)threadIdx.x * NBAC + blockIdx.x] = s;
    }
}

// ---------------- k1f: reduce partials -> accum[65] ----------------
__global__ void k1_final(const float* __restrict__ partial, float* __restrict__ accum)
{
    const int e = blockIdx.x, lane = threadIdx.x;
    float s = 0.f;
#pragma unroll
    for (int i = 0; i < NBAC / 64; ++i) s += partial[(size_t)e * NBAC + i * 64 + lane];
#pragma unroll
    for (int sh = 1; sh < 64; sh <<= 1) s += __shfl_xor(s, sh, 64);
    if (lane == 0) accum[e] = s;
}

// ---------------- k2: finalize BN -> folded W', b' ----------------
__global__ void k2_finalize(const float* __restrict__ accum, const float* __restrict__ W,
                            const float* __restrict__ b, const float* __restrict__ gamma,
                            const float* __restrict__ beta, float* __restrict__ Wp,
                            float* __restrict__ bp)
{
    int c = threadIdx.x;
    if (c >= 32) return;
    const float invN = 1.0f / (float)NPTS;
    float m[10], w[10];
#pragma unroll
    for (int k = 0; k < 10; ++k) m[k] = accum[k] * invN;
#pragma unroll
    for (int k = 0; k < 10; ++k) w[k] = W[c*10 + k];
    float mean = b[c];
#pragma unroll
    for (int k = 0; k < 10; ++k) mean += w[k] * m[k];
    float var = 0.f;
#pragma unroll
    for (int j = 0; j < 10; ++j) {
#pragma unroll
        for (int k = j; k < 10; ++k) {
            float Cjk = accum[10 + tri_idx(j, k)] * invN - m[j] * m[k];
            var += w[j] * w[k] * Cjk * ((j == k) ? 1.f : 2.f);
        }
    }
    float scale = gamma[c] * rsqrtf(var + BN_EPS_F);
#pragma unroll
    for (int k = 0; k < 10; ++k) Wp[c*10 + k] = w[k] * scale;
    bp[c] = (b[c] - mean) * scale + beta[c];
}

// ---------------- kD7: channel-per-lane, LDS double-buffered record pipeline ----------------
__device__ __forceinline__ float kd_affine(const float4& v0, const float4& v1,
                                           const float4& v2, const float* w, float bc)
{
    float a = bc;
    a += v0.x * w[0]; a += v0.y * w[1]; a += v0.z * w[2]; a += v0.w * w[3];
    a += v1.x * w[4]; a += v1.y * w[5]; a += v1.z * w[6]; a += v1.w * w[7];
    a += v2.x * w[8]; a += v2.y * w[9];
    return fmaxf(a, 0.f);
}

__global__ __launch_bounds__(256) void kD7_reduce(const float* __restrict__ psf,
                                                  const unsigned* __restrict__ starts,
                                                  const float* __restrict__ Wp,
                                                  const float* __restrict__ bp,
                                                  float* __restrict__ out)
{
    __shared__ unsigned tab[PPB * 32];   // 4 KB; tab[pl*32+c] -> bank c, 2-way free
    __shared__ float sbuf[2][TDW];       // 2 x 3 KB record chunks
    for (int i = threadIdx.x; i < PPB * 32; i += 256) tab[i] = 0u;

    const int c   = threadIdx.x & 31;
    const int sub = threadIdx.x >> 5;    // 0..7
    float w[10];
#pragma unroll
    for (int k = 0; k < 10; ++k) w[k] = Wp[c * 10 + k];
    const float bc = bp[c];

    const unsigned s0 = starts[blockIdx.x];
    const unsigned s1 = starts[blockIdx.x + 1];
    const unsigned nrec = s1 - s0;
    const int nch = (int)((nrec + TILE - 1) / TILE);
    const size_t gbase  = (size_t)s0 * 12;          // dword offset into psf
    const size_t gend   = (size_t)NPTS * 12;        // total dwords in ps stream

    float st[3];
    // prologue: stage chunk 0
    if (nch > 0) {
        size_t cb = gbase;
        if (cb + TDW <= gend) {
#pragma unroll
            for (int j = 0; j < 3; ++j) st[j] = psf[cb + threadIdx.x + j * 256];
        } else {
#pragma unroll
            for (int j = 0; j < 3; ++j) {
                size_t gi = cb + threadIdx.x + j * 256;
                st[j] = psf[gi < gend ? gi : gend - 1];
            }
        }
#pragma unroll
        for (int j = 0; j < 3; ++j) sbuf[0][threadIdx.x + j * 256] = st[j];
    }
    __syncthreads();

    // ---- phase 1: max into LDS table ----
    for (int ci = 0; ci < nch; ++ci) {
        const bool more = (ci + 1 < nch);
        if (more) {
            size_t cb = gbase + (size_t)(ci + 1) * TDW;
            if (cb + TDW <= gend) {
#pragma unroll
                for (int j = 0; j < 3; ++j) st[j] = psf[cb + threadIdx.x + j * 256];
            } else {
#pragma unroll
                for (int j = 0; j < 3; ++j) {
                    size_t gi = cb + threadIdx.x + j * 256;
                    st[j] = psf[gi < gend ? gi : gend - 1];
                }
            }
        }
        const float4* s4 = reinterpret_cast<const float4*>(sbuf[ci & 1]);
        int rem = (int)nrec - ci * TILE;
        int rmax = rem < TILE ? rem : TILE;
        for (int r = sub; r < rmax; r += 8) {
            float4 v0 = s4[r * 3], v1 = s4[r * 3 + 1], v2 = s4[r * 3 + 2];
            unsigned meta = __float_as_uint(v2.z);
            unsigned pl = (meta >> 21) & (PPB - 1);
            float a = kd_affine(v0, v1, v2, w, bc);
            atomicMax(&tab[(pl << 5) + c], __float_as_uint(a));
        }
        __syncthreads();
        if (more) {
#pragma unroll
            for (int j = 0; j < 3; ++j) sbuf[(ci + 1) & 1][threadIdx.x + j * 256] = st[j];
        }
        __syncthreads();
    }

    // ---- phase 2: recompute from re-staged stream, combine, store ----
    if (nch > 0) {
        size_t cb = gbase;
        if (cb + TDW <= gend) {
#pragma unroll
            for (int j = 0; j < 3; ++j) st[j] = psf[cb + threadIdx.x + j * 256];
        } else {
#pragma unroll
            for (int j = 0; j < 3; ++j) {
                size_t gi = cb + threadIdx.x + j * 256;
                st[j] = psf[gi < gend ? gi : gend - 1];
            }
        }
#pragma unroll
        for (int j = 0; j < 3; ++j) sbuf[0][threadIdx.x + j * 256] = st[j];
    }
    __syncthreads();

    for (int ci = 0; ci < nch; ++ci) {
        const bool more = (ci + 1 < nch);
        if (more) {
            size_t cb = gbase + (size_t)(ci + 1) * TDW;
            if (cb + TDW <= gend) {
#pragma unroll
                for (int j = 0; j < 3; ++j) st[j] = psf[cb + threadIdx.x + j * 256];
            } else {
#pragma unroll
                for (int j = 0; j < 3; ++j) {
                    size_t gi = cb + threadIdx.x + j * 256;
                    st[j] = psf[gi < gend ? gi : gend - 1];
                }
            }
        }
        const float4* s4 = reinterpret_cast<const float4*>(sbuf[ci & 1]);
        int rem = (int)nrec - ci * TILE;
        int rmax = rem < TILE ? rem : TILE;
        for (int r = sub; r < rmax; r += 8) {
            float4 v0 = s4[r * 3], v1 = s4[r * 3 + 1], v2 = s4[r * 3 + 2];
            unsigned meta = __float_as_uint(v2.z);
            unsigned idx = meta & 0x1FFFFFu;
            unsigned pl = (meta >> 21) & (PPB - 1);
            float a = kd_affine(v0, v1, v2, w, bc);
            float mx = __uint_as_float(tab[(pl << 5) + c]);
            __builtin_nontemporal_store((a + mx) * 0.5f, &out[(size_t)idx * 32 + c]);
        }
        __syncthreads();
        if (more) {
#pragma unroll
            for (int j = 0; j < 3; ++j) sbuf[(ci + 1) & 1][threadIdx.x + j * 256] = st[j];
        }
        __syncthreads();
    }
}

extern "C" void kernel_launch(void* const* d_in, const int* in_sizes, int n_in,
                              void* d_out, int out_size, void* d_ws, size_t ws_size,
                              hipStream_t stream)
{
    const float* in    = (const float*)d_in[0];
    const float* W     = (const float*)d_in[1];
    const float* b     = (const float*)d_in[2];
    const float* gamma = (const float*)d_in[3];
    const float* beta  = (const float*)d_in[4];
    const int*   unq   = (const int*)d_in[5];

    float* ws      = (float*)d_ws;
    float* accum   = ws + ACC_OFF;
    float* Wp      = ws + WP_OFF;
    float* bp      = ws + BP_OFF;
    float* partial = ws + PART_OFF;
    unsigned* tots   = (unsigned*)(ws + TOTS_OFF);
    unsigned* starts = (unsigned*)(ws + STARTS_OFF);
    unsigned* hist   = (unsigned*)(ws + HIST_OFF);   // becomes offsets after kB3
    float4*   ps4    = (float4*)(ws + PS_OFF);

    // bucket histogram (unq only) -> offsets
    kA_hist<<<NBAC, 512, 0, stream>>>(unq, hist);
    kB1_colsum<<<NBKT, 64, 0, stream>>>(hist, tots);
    kB2_scan<<<1, 1024, 0, stream>>>(tots, starts);
    kB3_expand<<<NBKT, 64, 0, stream>>>(hist, starts);
    // sort full records + accumulate all 65 input moments in the same pass
    kC2_scatter_mom<<<NBAC, 512, 0, stream>>>(in, unq, hist, ps4, partial);
    // BN fold
    k1_final<<<65, 64, 0, stream>>>(partial, accum);
    k2_finalize<<<1, 64, 0, stream>>>(accum, W, b, gamma, beta, Wp, bp);
    // per-bucket LDS segment-max + fused output (double-buffered record pipeline)
    kD7_reduce<<<NBKT, 256, 0, stream>>>((const float*)ps4, starts, Wp, bp, (float*)d_out);
}